// Round 2
// baseline (2306.782 us; speedup 1.0000x reference)
//
#include <hip/hip_runtime.h>
#include <hip/hip_bf16.h>
#include <math.h>

#define N_TOK 5000
#define EMB_D 256
#define HEADS 8
#define DEPTH 32
#define W_DIM 100
#define H_DIM 50
#define PIX 8

// ---------------------------------------------------------------------------
// Kernel 0: detect mask dtype. Word mask (int32/float32) -> words in
// {0, 1, 0x3F800000}; byte mask (bool) -> random bytes, first 1024 words
// essentially never all in that set. flag=1 -> byte mask.
// ---------------------------------------------------------------------------
__global__ void detect_mask_kernel(const unsigned int* __restrict__ mask,
                                   int* __restrict__ flag) {
    if (threadIdx.x == 0 && blockIdx.x == 0) {
        int bytes = 0;
        for (int i = 0; i < 1024; ++i) {
            unsigned int w = mask[i];
            if (w != 0u && w != 1u && w != 0x3F800000u) { bytes = 1; break; }
        }
        *flag = bytes;
    }
}

// ---------------------------------------------------------------------------
// Kernel A: fused (img + pos) -> token embed -> {Q | K,V} projection
// grid (625, 2): y==0 -> x -> Q ; y==1 -> context -> K,V. block=256.
// ---------------------------------------------------------------------------
__global__ __launch_bounds__(256) void embed_qkv_kernel(
    const float* __restrict__ x, const float* __restrict__ ctx,
    const float* __restrict__ row_embed, const float* __restrict__ col_embed,
    const float* __restrict__ w_in, const float* __restrict__ b_in,
    const float* __restrict__ wq, const float* __restrict__ bq,
    const float* __restrict__ wk, const float* __restrict__ bk,
    const float* __restrict__ wv, const float* __restrict__ bv,
    float* __restrict__ Qg, float* __restrict__ Kg, float* __restrict__ Vg)
{
    __shared__ __align__(16) float ysh[PIX][EMB_D];
    __shared__ __align__(16) float tsh[PIX][EMB_D];
    const int t  = threadIdx.x;
    const int n0 = blockIdx.x * PIX;
    const int which = blockIdx.y;
    const float* img = which ? ctx : x;

    // phase 1: y = img + pos  (thread t == channel c)
    {
        const int c = t;
        float4 v0 = *(const float4*)(img + c * N_TOK + n0);
        float4 v1 = *(const float4*)(img + c * N_TOK + n0 + 4);
        float vv[8] = {v0.x, v0.y, v0.z, v0.w, v1.x, v1.y, v1.z, v1.w};
        #pragma unroll
        for (int p = 0; p < PIX; ++p) {
            int n  = n0 + p;
            int hh = n / W_DIM;
            int ww = n - hh * W_DIM;
            float pos = (c < 128) ? col_embed[ww * 128 + c]
                                  : row_embed[hh * 128 + (c - 128)];
            ysh[p][c] = vv[p] + pos;
        }
    }
    __syncthreads();

    // phase 2: tok[e] = b_in[e] + sum_c w_in[e][c] * y[c]
    {
        const int e = t;
        float acc[PIX];
        #pragma unroll
        for (int p = 0; p < PIX; ++p) acc[p] = 0.f;
        for (int c = 0; c < EMB_D; c += 4) {
            float4 w4 = *(const float4*)(w_in + e * EMB_D + c);
            #pragma unroll
            for (int p = 0; p < PIX; ++p) {
                float4 y4 = *(const float4*)&ysh[p][c];
                acc[p] += w4.x * y4.x + w4.y * y4.y + w4.z * y4.z + w4.w * y4.w;
            }
        }
        float bb = b_in[e];
        #pragma unroll
        for (int p = 0; p < PIX; ++p) tsh[p][e] = acc[p] + bb;
    }
    __syncthreads();

    // phase 3: project tokens with wq (which==0) or wk,wv (which==1)
    {
        const int e = t;
        const int head = e >> 5, d = e & 31;
        const float* wmat[2];
        const float* bvec[2];
        float*       outg[2];
        int nm;
        if (which == 0) { wmat[0] = wq; bvec[0] = bq; outg[0] = Qg; nm = 1; }
        else            { wmat[0] = wk; bvec[0] = bk; outg[0] = Kg;
                          wmat[1] = wv; bvec[1] = bv; outg[1] = Vg; nm = 2; }
        for (int mi = 0; mi < nm; ++mi) {
            const float* wm = wmat[mi];
            float acc[PIX];
            #pragma unroll
            for (int p = 0; p < PIX; ++p) acc[p] = 0.f;
            for (int c = 0; c < EMB_D; c += 4) {
                float4 w4 = *(const float4*)(wm + e * EMB_D + c);
                #pragma unroll
                for (int p = 0; p < PIX; ++p) {
                    float4 y4 = *(const float4*)&tsh[p][c];
                    acc[p] += w4.x * y4.x + w4.y * y4.y + w4.z * y4.z + w4.w * y4.w;
                }
            }
            float bb = bvec[mi][e];
            float* og = outg[mi];
            #pragma unroll
            for (int p = 0; p < PIX; ++p)
                og[head * (N_TOK * DEPTH) + (size_t)(n0 + p) * DEPTH + d] = acc[p] + bb;
        }
    }
}

// ---------------------------------------------------------------------------
// Kernel B: flash attention. block=256 threads, each thread owns (q_local, head).
// grid = ceil(5000/32) = 157 blocks; K/V for all 8 heads staged per 32-key tile.
// ---------------------------------------------------------------------------
__global__ __launch_bounds__(256) void attn_kernel(
    const float* __restrict__ Qg, const float* __restrict__ Kg,
    const float* __restrict__ Vg, const void* __restrict__ mask_raw,
    const int* __restrict__ mask_flag, float* __restrict__ AO)
{
    __shared__ __align__(16) float Kl[32][EMB_D];   // [key][head*32+d]  32KB
    __shared__ __align__(16) float Vl[32][EMB_D];   //                   32KB
    __shared__ int ml[32][33];                       // padded mask tile

    const int t = threadIdx.x;
    const int q_local = t & 31;
    const int head    = t >> 5;
    const int qi0 = blockIdx.x * 32;
    const int qi  = qi0 + q_local;
    const bool valid = qi < N_TOK;
    const int mbytes = *mask_flag;   // 1 -> byte mask, 0 -> word mask

    float qreg[DEPTH];
    if (valid) {
        #pragma unroll
        for (int i = 0; i < DEPTH; i += 4) {
            float4 v = *(const float4*)(Qg + head * (N_TOK * DEPTH) + (size_t)qi * DEPTH + i);
            qreg[i] = v.x; qreg[i+1] = v.y; qreg[i+2] = v.z; qreg[i+3] = v.w;
        }
    } else {
        #pragma unroll
        for (int i = 0; i < DEPTH; ++i) qreg[i] = 0.f;
    }

    float m = -INFINITY, l = 0.f;
    float o[DEPTH];
    #pragma unroll
    for (int i = 0; i < DEPTH; ++i) o[i] = 0.f;
    const float scale = 0.0625f;  // 256^-0.5

    const int ntile = (N_TOK + 31) / 32;  // 157
    for (int kt = 0; kt < ntile; ++kt) {
        const int k0 = kt * 32;
        const int nk = min(32, N_TOK - k0);
        __syncthreads();
        // stage K,V tiles (all heads): 2048 float4 each
        #pragma unroll
        for (int i = 0; i < 8; ++i) {
            int f = t + 256 * i;        // float4 index 0..2047
            int j = f >> 6;             // key row
            int r = f & 63;
            int hh = r >> 3;
            int dd = (r & 7) << 2;
            if (j < nk) {
                *(float4*)&Kl[j][hh * DEPTH + dd] =
                    *(const float4*)(Kg + hh * (N_TOK * DEPTH) + (size_t)(k0 + j) * DEPTH + dd);
                *(float4*)&Vl[j][hh * DEPTH + dd] =
                    *(const float4*)(Vg + hh * (N_TOK * DEPTH) + (size_t)(k0 + j) * DEPTH + dd);
            }
        }
        // stage mask tile: thread t covers row=t>>3 (0..31), col4=t&7 (4 cols)
        {
            int row  = t >> 3, col4 = t & 7;
            int qrow = qi0 + row;
            if (qrow < N_TOK && col4 * 4 < nk) {
                if (mbytes) {
                    const unsigned int* mu = (const unsigned int*)mask_raw;
                    unsigned int w = mu[(size_t)qrow * (N_TOK / 4) + (k0 >> 2) + col4];
                    ml[row][col4 * 4 + 0] = (int)( w        & 0xFFu);
                    ml[row][col4 * 4 + 1] = (int)((w >> 8)  & 0xFFu);
                    ml[row][col4 * 4 + 2] = (int)((w >> 16) & 0xFFu);
                    ml[row][col4 * 4 + 3] = (int)((w >> 24) & 0xFFu);
                } else {
                    const int* mi32 = (const int*)mask_raw;
                    int4 mv = *(const int4*)(mi32 + (size_t)qrow * N_TOK + k0 + col4 * 4);
                    ml[row][col4 * 4 + 0] = mv.x;
                    ml[row][col4 * 4 + 1] = mv.y;
                    ml[row][col4 * 4 + 2] = mv.z;
                    ml[row][col4 * 4 + 3] = mv.w;
                }
            }
        }
        __syncthreads();
        if (!valid) continue;

        float s[32];
        float tm = -INFINITY;
        #pragma unroll
        for (int j = 0; j < 32; ++j) {
            float sv = -INFINITY;
            if (j < nk && !ml[q_local][j]) {
                float acc = 0.f;
                #pragma unroll
                for (int i = 0; i < DEPTH; i += 4) {
                    float4 kv = *(const float4*)&Kl[j][head * DEPTH + i];
                    acc += kv.x * qreg[i] + kv.y * qreg[i+1] + kv.z * qreg[i+2] + kv.w * qreg[i+3];
                }
                sv = acc * scale;
                tm = fmaxf(tm, sv);
            }
            s[j] = sv;
        }
        if (tm == -INFINITY) continue;   // whole tile masked for this row

        float m_new = fmaxf(m, tm);
        float corr = __expf(m - m_new);  // exp(-inf)=0 handles first tile
        l *= corr;
        #pragma unroll
        for (int i = 0; i < DEPTH; ++i) o[i] *= corr;
        m = m_new;

        #pragma unroll
        for (int j = 0; j < 32; ++j) {
            float p = __expf(s[j] - m);  // masked / j>=nk -> exp(-inf)=0
            l += p;
            #pragma unroll
            for (int i = 0; i < DEPTH; i += 4) {
                float4 vv = *(const float4*)&Vl[j][head * DEPTH + i];
                o[i]   += p * vv.x; o[i+1] += p * vv.y;
                o[i+2] += p * vv.z; o[i+3] += p * vv.w;
            }
        }
    }

    if (valid) {
        float inv = 1.f / l;
        #pragma unroll
        for (int i = 0; i < DEPTH; i += 4) {
            float4 ov;
            ov.x = o[i] * inv; ov.y = o[i+1] * inv;
            ov.z = o[i+2] * inv; ov.w = o[i+3] * inv;
            *(float4*)(AO + (size_t)qi * EMB_D + head * DEPTH + i) = ov;
        }
    }
}

// ---------------------------------------------------------------------------
// Kernel C: output projection out[c,n] = b_out[c] + sum_e w_out[c][e]*AO[n][e]
// ---------------------------------------------------------------------------
__global__ __launch_bounds__(256) void proj_out_kernel(
    const float* __restrict__ AO, const float* __restrict__ w_out,
    const float* __restrict__ b_out, float* __restrict__ out)
{
    __shared__ __align__(16) float a[PIX][EMB_D];
    const int t  = threadIdx.x;
    const int n0 = blockIdx.x * PIX;
    #pragma unroll
    for (int i = 0; i < 2; ++i) {
        int f = t + 256 * i;        // float4 idx 0..511 = 8 pixels x 64 float4
        int p = f >> 6, e4 = f & 63;
        *(float4*)&a[p][e4 * 4] = *(const float4*)(AO + (size_t)(n0 + p) * EMB_D + e4 * 4);
    }
    __syncthreads();

    const int c = t;
    float acc[PIX];
    #pragma unroll
    for (int p = 0; p < PIX; ++p) acc[p] = 0.f;
    for (int e = 0; e < EMB_D; e += 4) {
        float4 w4 = *(const float4*)(w_out + c * EMB_D + e);
        #pragma unroll
        for (int p = 0; p < PIX; ++p) {
            float4 a4 = *(const float4*)&a[p][e];
            acc[p] += w4.x * a4.x + w4.y * a4.y + w4.z * a4.z + w4.w * a4.w;
        }
    }
    float bb = b_out[c];
    float4 r0, r1;
    r0.x = acc[0] + bb; r0.y = acc[1] + bb; r0.z = acc[2] + bb; r0.w = acc[3] + bb;
    r1.x = acc[4] + bb; r1.y = acc[5] + bb; r1.z = acc[6] + bb; r1.w = acc[7] + bb;
    *(float4*)(out + (size_t)c * N_TOK + n0)     = r0;
    *(float4*)(out + (size_t)c * N_TOK + n0 + 4) = r1;
}

// ---------------------------------------------------------------------------
extern "C" void kernel_launch(void* const* d_in, const int* in_sizes, int n_in,
                              void* d_out, int out_size, void* d_ws, size_t ws_size,
                              hipStream_t stream) {
    const float* x         = (const float*)d_in[0];
    const float* ctx       = (const float*)d_in[1];
    const void*  mask      = (const void*) d_in[2];
    const float* row_embed = (const float*)d_in[3];
    const float* col_embed = (const float*)d_in[4];
    const float* w_in      = (const float*)d_in[5];
    const float* b_in      = (const float*)d_in[6];
    const float* wq        = (const float*)d_in[7];
    const float* bq        = (const float*)d_in[8];
    const float* wk        = (const float*)d_in[9];
    const float* bk        = (const float*)d_in[10];
    const float* wv        = (const float*)d_in[11];
    const float* bv        = (const float*)d_in[12];
    const float* w_out     = (const float*)d_in[13];
    const float* b_out     = (const float*)d_in[14];
    float* out = (float*)d_out;

    float* ws = (float*)d_ws;
    float* Qg = ws;                 // [8][5000][32]
    float* Kg = ws + 1280000;
    float* Vg = ws + 2560000;
    float* AO = ws + 3840000;       // [5000][256]
    int*   mask_flag = (int*)(ws + 5120000);

    detect_mask_kernel<<<1, 64, 0, stream>>>((const unsigned int*)mask, mask_flag);
    embed_qkv_kernel<<<dim3(625, 2), 256, 0, stream>>>(
        x, ctx, row_embed, col_embed, w_in, b_in, wq, bq, wk, bk, wv, bv, Qg, Kg, Vg);
    attn_kernel<<<dim3(157), 256, 0, stream>>>(Qg, Kg, Vg, mask, mask_flag, AO);
    proj_out_kernel<<<dim3(625), 256, 0, stream>>>(AO, w_out, b_out, out);
}

// Round 3
// 480.143 us; speedup vs baseline: 4.8044x; 4.8044x over previous
//
#include <hip/hip_runtime.h>
#include <hip/hip_bf16.h>
#include <math.h>

#define N_TOK 5000
#define EMB_D 256
#define HEADS 8
#define DEPTH 32
#define W_DIM 100
#define PIX 8
#define TPAD 5056
#define VTP  5120
#define QPAD 5056
#define NKT  157

typedef __attribute__((ext_vector_type(8)))  short short8_t;
typedef __attribute__((ext_vector_type(16))) float f32x16;

__device__ __forceinline__ unsigned f2bf(float x) {
    union { float f; unsigned u; } c; c.f = x;
    return (c.u + 0x8000u) >> 16;
}
__device__ __forceinline__ unsigned pack2bf(float lo, float hi) {
    union { float f; unsigned u; } a, b; a.f = lo; b.f = hi;
    return ((a.u + 0x8000u) >> 16) | ((b.u + 0x8000u) & 0xFFFF0000u);
}

// ---------------------------------------------------------------------------
// Kernel 0: detect mask dtype (word 0/1/1.0f vs packed bytes). 1 wave.
// ---------------------------------------------------------------------------
__global__ void detect_mask_kernel(const unsigned* __restrict__ mask,
                                   int* __restrict__ flag) {
    int t = threadIdx.x;
    bool bad = false;
    for (int i = 0; i < 16; ++i) {
        unsigned w = mask[t * 16 + i];
        if (w != 0u && w != 1u && w != 0x3F800000u) bad = true;
    }
    unsigned long long bb = __ballot(bad);
    if (t == 0) *flag = (bb != 0ull) ? 1 : 0;
}

// ---------------------------------------------------------------------------
// Kernel 1: pack mask to bits, transposed: pmT[kt][q] bit j = masked(q, kt*32+j)
// ---------------------------------------------------------------------------
__global__ __launch_bounds__(256) void pack_mask_kernel(
    const void* __restrict__ mask_raw, const int* __restrict__ flag,
    unsigned* __restrict__ pmT)
{
    int q  = blockIdx.x * 256 + threadIdx.x;
    int kt = blockIdx.y;
    if (q >= N_TOK) return;
    int k0 = kt * 32;
    unsigned bits = 0;
    if (*flag) {  // byte mask
        const unsigned* src = (const unsigned*)((const char*)mask_raw + ((size_t)q * N_TOK + k0));
        #pragma unroll
        for (int w = 0; w < 8; ++w) {
            unsigned u = src[w];
            #pragma unroll
            for (int b = 0; b < 4; ++b)
                if (u & (0xFFu << (8 * b))) bits |= 1u << (4 * w + b);
        }
    } else {      // int32 mask
        const int4* src = (const int4*)((const int*)mask_raw + (size_t)q * N_TOK + k0);
        #pragma unroll
        for (int w = 0; w < 8; ++w) {
            int4 u = src[w];
            if (u.x) bits |= 1u << (4 * w + 0);
            if (u.y) bits |= 1u << (4 * w + 1);
            if (u.z) bits |= 1u << (4 * w + 2);
            if (u.w) bits |= 1u << (4 * w + 3);
        }
    }
    if (k0 + 32 > N_TOK) {
        #pragma unroll
        for (int j = 0; j < 32; ++j)
            if (k0 + j >= N_TOK) bits |= 1u << j;
    }
    pmT[(size_t)kt * QPAD + q] = bits;
}

// ---------------------------------------------------------------------------
// Kernel 2: fused (img + pos) -> token embed -> {Q | K,V} projection, bf16 out.
// Q,K: [head][token(TPAD)][32] bf16.  V: transposed [head][32][VTP] bf16.
// ---------------------------------------------------------------------------
__global__ __launch_bounds__(256) void embed_qkv_kernel(
    const float* __restrict__ x, const float* __restrict__ ctx,
    const float* __restrict__ row_embed, const float* __restrict__ col_embed,
    const float* __restrict__ w_in, const float* __restrict__ b_in,
    const float* __restrict__ wq, const float* __restrict__ bq,
    const float* __restrict__ wk, const float* __restrict__ bk,
    const float* __restrict__ wv, const float* __restrict__ bv,
    unsigned short* __restrict__ Qb, unsigned short* __restrict__ Kb,
    unsigned short* __restrict__ Vt)
{
    __shared__ __align__(16) float ysh[PIX][EMB_D];
    __shared__ __align__(16) float tsh[PIX][EMB_D];
    const int t  = threadIdx.x;
    const int n0 = blockIdx.x * PIX;
    const int which = blockIdx.y;
    const float* img = which ? ctx : x;

    {   // phase 1: y = img + pos
        const int c = t;
        float4 v0 = *(const float4*)(img + c * N_TOK + n0);
        float4 v1 = *(const float4*)(img + c * N_TOK + n0 + 4);
        float vv[8] = {v0.x, v0.y, v0.z, v0.w, v1.x, v1.y, v1.z, v1.w};
        #pragma unroll
        for (int p = 0; p < PIX; ++p) {
            int n  = n0 + p;
            int hh = n / W_DIM;
            int ww = n - hh * W_DIM;
            float pos = (c < 128) ? col_embed[ww * 128 + c]
                                  : row_embed[hh * 128 + (c - 128)];
            ysh[p][c] = vv[p] + pos;
        }
    }
    __syncthreads();

    {   // phase 2: token embed
        const int e = t;
        float acc[PIX];
        #pragma unroll
        for (int p = 0; p < PIX; ++p) acc[p] = 0.f;
        for (int c = 0; c < EMB_D; c += 4) {
            float4 w4 = *(const float4*)(w_in + e * EMB_D + c);
            #pragma unroll
            for (int p = 0; p < PIX; ++p) {
                float4 y4 = *(const float4*)&ysh[p][c];
                acc[p] += w4.x * y4.x + w4.y * y4.y + w4.z * y4.z + w4.w * y4.w;
            }
        }
        float bb = b_in[e];
        #pragma unroll
        for (int p = 0; p < PIX; ++p) tsh[p][e] = acc[p] + bb;
    }
    __syncthreads();

    {   // phase 3: Q or K,V projection
        const int e = t;
        const int head = e >> 5, d = e & 31;
        const int nm = which ? 2 : 1;
        for (int mi = 0; mi < nm; ++mi) {
            const float* wm = which ? (mi ? wv : wk) : wq;
            const float* bb_ = which ? (mi ? bv : bk) : bq;
            float acc[PIX];
            #pragma unroll
            for (int p = 0; p < PIX; ++p) acc[p] = 0.f;
            for (int c = 0; c < EMB_D; c += 4) {
                float4 w4 = *(const float4*)(wm + e * EMB_D + c);
                #pragma unroll
                for (int p = 0; p < PIX; ++p) {
                    float4 y4 = *(const float4*)&tsh[p][c];
                    acc[p] += w4.x * y4.x + w4.y * y4.y + w4.z * y4.z + w4.w * y4.w;
                }
            }
            float bbv = bb_[e];
            if (which && mi == 1) {
                // V: transposed row e = head*32+d, tokens n0..n0+7 contiguous
                union { unsigned u[4]; short8_t v; } pk;
                #pragma unroll
                for (int p2 = 0; p2 < 4; ++p2)
                    pk.u[p2] = pack2bf(acc[2 * p2] + bbv, acc[2 * p2 + 1] + bbv);
                *(short8_t*)(Vt + (size_t)e * VTP + n0) = pk.v;
            } else {
                unsigned short* dst = (which ? Kb : Qb);
                #pragma unroll
                for (int p = 0; p < PIX; ++p)
                    dst[(size_t)head * TPAD * 32 + (size_t)(n0 + p) * 32 + d] =
                        (unsigned short)f2bf(acc[p] + bbv);
            }
        }
    }
}

// ---------------------------------------------------------------------------
// Kernel 3: MFMA flash attention. Block = 4 waves = 2 qtiles x 2 ksplits.
// Wave: 32 queries x 1 head, swapped QK^T (S^T), O^T = V^T . P^T.
// ---------------------------------------------------------------------------
__global__ __launch_bounds__(256) void attn_mfma_kernel(
    const unsigned short* __restrict__ Qb, const unsigned short* __restrict__ Kb,
    const unsigned short* __restrict__ Vt, const unsigned* __restrict__ pmT,
    float* __restrict__ AO)
{
    __shared__ float comb[2][18][64];

    const int t    = threadIdx.x;
    const int lane = t & 63;
    const int wid  = t >> 6;
    const int qsub = wid >> 1, ks = wid & 1;
    const int head = blockIdx.y;
    const int q0   = (blockIdx.x * 2 + qsub) * 32;
    const int l31  = lane & 31;
    const int h    = lane >> 5;
    const int grp8 = h * 8;
    const float scale = 0.0625f;           // 256^-0.5
    const float LOG2E = 1.4426950408889634f;

    const unsigned short* Kh = Kb + (size_t)head * TPAD * 32;
    const unsigned short* Qh = Qb + (size_t)head * TPAD * 32;
    const unsigned short* Vh = Vt + ((size_t)head * 32 + l31) * VTP;

    short8_t qf0 = *(const short8_t*)(Qh + (size_t)(q0 + l31) * 32 + grp8);
    short8_t qf1 = *(const short8_t*)(Qh + (size_t)(q0 + l31) * 32 + 16 + grp8);

    f32x16 oacc;
    #pragma unroll
    for (int r = 0; r < 16; ++r) oacc[r] = 0.f;
    float m = -INFINITY, lsum = 0.f;

    const int kt0 = ks ? 79 : 0;
    const int kt1 = ks ? NKT : 79;

    short8_t ka0, ka1, va0, va1; unsigned mw;
    {   // preload first tile
        int k0 = kt0 * 32;
        const unsigned short* kp = Kh + (size_t)(k0 + l31) * 32 + grp8;
        ka0 = *(const short8_t*)kp;
        ka1 = *(const short8_t*)(kp + 16);
        va0 = *(const short8_t*)(Vh + k0 + grp8);
        va1 = *(const short8_t*)(Vh + k0 + 16 + grp8);
        mw  = pmT[(size_t)kt0 * QPAD + q0 + l31];
    }

    for (int kt = kt0; kt < kt1; ++kt) {
        // prefetch next tile (clamped)
        int ktn = (kt + 1 < kt1) ? kt + 1 : kt;
        int k0n = ktn * 32;
        const unsigned short* kpn = Kh + (size_t)(k0n + l31) * 32 + grp8;
        short8_t nka0 = *(const short8_t*)kpn;
        short8_t nka1 = *(const short8_t*)(kpn + 16);
        short8_t nva0 = *(const short8_t*)(Vh + k0n + grp8);
        short8_t nva1 = *(const short8_t*)(Vh + k0n + 16 + grp8);
        unsigned nmw  = pmT[(size_t)ktn * QPAD + q0 + l31];

        // S^T = K . Q^T   (rows: keys, cols: queries)
        f32x16 sacc;
        #pragma unroll
        for (int r = 0; r < 16; ++r) sacc[r] = 0.f;
        sacc = __builtin_amdgcn_mfma_f32_32x32x16_bf16(ka0, qf0, sacc, 0, 0, 0);
        sacc = __builtin_amdgcn_mfma_f32_32x32x16_bf16(ka1, qf1, sacc, 0, 0, 0);

        float s[16];
        float mt = -INFINITY;
        #pragma unroll
        for (int r = 0; r < 16; ++r) { s[r] = sacc[r] * scale; mt = fmaxf(mt, s[r]); }
        mt = fmaxf(mt, __shfl_xor(mt, 32));

        float mn = fmaxf(m, mt);
        float corr = __expf(m - mn);       // exp(-inf)=0 on first tile
        m = mn;
        lsum *= corr;
        #pragma unroll
        for (int r = 0; r < 16; ++r) oacc[r] *= corr;

        float mbias = m * LOG2E;
        unsigned wg[4];
        wg[0] = mw >> (4 * h);      wg[1] = mw >> (8 + 4 * h);
        wg[2] = mw >> (16 + 4 * h); wg[3] = mw >> (24 + 4 * h);

        float pf[16];
        #pragma unroll
        for (int r = 0; r < 16; ++r) {
            float p = exp2f(s[r] * LOG2E - mbias);
            p = ((wg[r >> 2] >> (r & 3)) & 1u) ? 0.f : p;
            pf[r] = p;
            lsum += p;
        }

        // build P^T B-frags and accumulate O^T
        const int oo = 4 * h, oe = 4 - 4 * h;
        #pragma unroll
        for (int c = 0; c < 2; ++c) {
            const int base = 8 * c;
            unsigned own0 = pack2bf(pf[base + oo + 0], pf[base + oo + 1]);
            unsigned own1 = pack2bf(pf[base + oo + 2], pf[base + oo + 3]);
            unsigned e0   = pack2bf(pf[base + oe + 0], pf[base + oe + 1]);
            unsigned e1   = pack2bf(pf[base + oe + 2], pf[base + oe + 3]);
            unsigned r0 = (unsigned)__shfl_xor((int)e0, 32);
            unsigned r1 = (unsigned)__shfl_xor((int)e1, 32);
            union { unsigned u[4]; short8_t v; } fr;
            fr.u[0] = h ? r0 : own0;
            fr.u[1] = h ? r1 : own1;
            fr.u[2] = h ? own0 : r0;
            fr.u[3] = h ? own1 : r1;
            oacc = __builtin_amdgcn_mfma_f32_32x32x16_bf16(c ? va1 : va0, fr.v, oacc, 0, 0, 0);
        }

        ka0 = nka0; ka1 = nka1; va0 = nva0; va1 = nva1; mw = nmw;
    }

    float lfull = lsum + __shfl_xor(lsum, 32);

    if (ks == 1) {
        comb[qsub][0][lane] = m;
        comb[qsub][1][lane] = lfull;
        #pragma unroll
        for (int r = 0; r < 16; ++r) comb[qsub][2 + r][lane] = oacc[r];
    }
    __syncthreads();
    if (ks == 0) {
        float m1 = comb[qsub][0][lane];
        float l1 = comb[qsub][1][lane];
        float ms = fmaxf(m, m1);
        float c0 = __expf(m - ms);
        float c1 = __expf(m1 - ms);
        float den = lfull * c0 + l1 * c1;
        float inv = 1.f / den;
        int q = q0 + l31;
        if (q < N_TOK) {
            #pragma unroll
            for (int u = 0; u < 4; ++u) {
                float4 vv;
                vv.x = (oacc[4 * u + 0] * c0 + comb[qsub][2 + 4 * u + 0][lane] * c1) * inv;
                vv.y = (oacc[4 * u + 1] * c0 + comb[qsub][2 + 4 * u + 1][lane] * c1) * inv;
                vv.z = (oacc[4 * u + 2] * c0 + comb[qsub][2 + 4 * u + 2][lane] * c1) * inv;
                vv.w = (oacc[4 * u + 3] * c0 + comb[qsub][2 + 4 * u + 3][lane] * c1) * inv;
                *(float4*)(AO + (size_t)q * EMB_D + head * 32 + 8 * u + 4 * h) = vv;
            }
        }
    }
}

// ---------------------------------------------------------------------------
// Kernel 4: output projection out[c,n] = b_out[c] + sum_e w_out[c][e]*AO[n][e]
// ---------------------------------------------------------------------------
__global__ __launch_bounds__(256) void proj_out_kernel(
    const float* __restrict__ AO, const float* __restrict__ w_out,
    const float* __restrict__ b_out, float* __restrict__ out)
{
    __shared__ __align__(16) float a[PIX][EMB_D];
    const int t  = threadIdx.x;
    const int n0 = blockIdx.x * PIX;
    #pragma unroll
    for (int i = 0; i < 2; ++i) {
        int f = t + 256 * i;        // 512 float4 = 8 pixels x 64 float4
        int p = f >> 6, e4 = f & 63;
        *(float4*)&a[p][e4 * 4] = *(const float4*)(AO + (size_t)(n0 + p) * EMB_D + e4 * 4);
    }
    __syncthreads();

    const int c = t;
    float acc[PIX];
    #pragma unroll
    for (int p = 0; p < PIX; ++p) acc[p] = 0.f;
    for (int e = 0; e < EMB_D; e += 4) {
        float4 w4 = *(const float4*)(w_out + c * EMB_D + e);
        #pragma unroll
        for (int p = 0; p < PIX; ++p) {
            float4 a4 = *(const float4*)&a[p][e];
            acc[p] += w4.x * a4.x + w4.y * a4.y + w4.z * a4.z + w4.w * a4.w;
        }
    }
    float bb = b_out[c];
    float4 r0, r1;
    r0.x = acc[0] + bb; r0.y = acc[1] + bb; r0.z = acc[2] + bb; r0.w = acc[3] + bb;
    r1.x = acc[4] + bb; r1.y = acc[5] + bb; r1.z = acc[6] + bb; r1.w = acc[7] + bb;
    *(float4*)(out + (size_t)c * N_TOK + n0)     = r0;
    *(float4*)(out + (size_t)c * N_TOK + n0 + 4) = r1;
}

// ---------------------------------------------------------------------------
extern "C" void kernel_launch(void* const* d_in, const int* in_sizes, int n_in,
                              void* d_out, int out_size, void* d_ws, size_t ws_size,
                              hipStream_t stream) {
    const float* x         = (const float*)d_in[0];
    const float* ctx       = (const float*)d_in[1];
    const void*  mask      = (const void*) d_in[2];
    const float* row_embed = (const float*)d_in[3];
    const float* col_embed = (const float*)d_in[4];
    const float* w_in      = (const float*)d_in[5];
    const float* b_in      = (const float*)d_in[6];
    const float* wq        = (const float*)d_in[7];
    const float* bq        = (const float*)d_in[8];
    const float* wk        = (const float*)d_in[9];
    const float* bk        = (const float*)d_in[10];
    const float* wv        = (const float*)d_in[11];
    const float* bv        = (const float*)d_in[12];
    const float* w_out     = (const float*)d_in[13];
    const float* b_out     = (const float*)d_in[14];
    float* out = (float*)d_out;

    char* ws = (char*)d_ws;
    unsigned short* Qb  = (unsigned short*)(ws);                    // 2,588,672 B
    unsigned short* Kb  = (unsigned short*)(ws + 2588672);          // 2,588,672 B
    unsigned short* Vt  = (unsigned short*)(ws + 5177344);          // 2,621,440 B
    unsigned*       pmT = (unsigned*)      (ws + 7798784);          // 3,175,168 B
    float*          AO  = (float*)         (ws + 10973952);         // 5,120,000 B
    int*       maskflag = (int*)           (ws + 16093952);

    detect_mask_kernel<<<1, 64, 0, stream>>>((const unsigned*)mask, maskflag);
    pack_mask_kernel<<<dim3(20, NKT), 256, 0, stream>>>(mask, maskflag, pmT);
    embed_qkv_kernel<<<dim3(625, 2), 256, 0, stream>>>(
        x, ctx, row_embed, col_embed, w_in, b_in, wq, bq, wk, bk, wv, bv, Qb, Kb, Vt);
    attn_mfma_kernel<<<dim3(79, 8), 256, 0, stream>>>(Qb, Kb, Vt, pmT, AO);
    proj_out_kernel<<<dim3(625), 256, 0, stream>>>(AO, w_out, b_out, out);
}

// Round 4
// 412.328 us; speedup vs baseline: 5.5945x; 1.1645x over previous
//
#include <hip/hip_runtime.h>
#include <hip/hip_bf16.h>
#include <math.h>

#define N_TOK 5000
#define EMB_D 256
#define HEADS 8
#define DEPTH 32
#define W_DIM 100
#define PIX 8
#define TPAD 5056
#define VTP  5120
#define QPAD 5056
#define NKT  157

typedef __attribute__((ext_vector_type(8)))  short short8_t;
typedef __attribute__((ext_vector_type(16))) float f32x16;

__device__ __forceinline__ unsigned f2bf(float x) {
    union { float f; unsigned u; } c; c.f = x;
    return (c.u + 0x8000u) >> 16;
}
__device__ __forceinline__ unsigned pack2bf(float lo, float hi) {
    __hip_bfloat162 h2 = __float22bfloat162_rn(make_float2(lo, hi));
    union { __hip_bfloat162 h; unsigned u; } c; c.h = h2;
    return c.u;
}

// ---------------------------------------------------------------------------
// Kernel 0: detect mask dtype (word 0/1/1.0f vs packed bytes). 1 wave.
// ---------------------------------------------------------------------------
__global__ void detect_mask_kernel(const unsigned* __restrict__ mask,
                                   int* __restrict__ flag) {
    int t = threadIdx.x;
    bool bad = false;
    for (int i = 0; i < 16; ++i) {
        unsigned w = mask[t * 16 + i];
        if (w != 0u && w != 1u && w != 0x3F800000u) bad = true;
    }
    unsigned long long bb = __ballot(bad);
    if (t == 0) *flag = (bb != 0ull) ? 1 : 0;
}

// ---------------------------------------------------------------------------
// Kernel 1: pack mask to bits, transposed: pmT[kt][q] bit j = masked(q, kt*32+j)
// ---------------------------------------------------------------------------
__global__ __launch_bounds__(256) void pack_mask_kernel(
    const void* __restrict__ mask_raw, const int* __restrict__ flag,
    unsigned* __restrict__ pmT)
{
    int q  = blockIdx.x * 256 + threadIdx.x;
    int kt = blockIdx.y;
    if (q >= N_TOK) return;
    int k0 = kt * 32;
    unsigned bits = 0;
    if (*flag) {  // byte mask
        const unsigned* src = (const unsigned*)((const char*)mask_raw + ((size_t)q * N_TOK + k0));
        #pragma unroll
        for (int w = 0; w < 8; ++w) {
            unsigned u = src[w];
            #pragma unroll
            for (int b = 0; b < 4; ++b)
                if (u & (0xFFu << (8 * b))) bits |= 1u << (4 * w + b);
        }
    } else {      // int32 mask
        const int4* src = (const int4*)((const int*)mask_raw + (size_t)q * N_TOK + k0);
        #pragma unroll
        for (int w = 0; w < 8; ++w) {
            int4 u = src[w];
            if (u.x) bits |= 1u << (4 * w + 0);
            if (u.y) bits |= 1u << (4 * w + 1);
            if (u.z) bits |= 1u << (4 * w + 2);
            if (u.w) bits |= 1u << (4 * w + 3);
        }
    }
    if (k0 + 32 > N_TOK) {
        #pragma unroll
        for (int j = 0; j < 32; ++j)
            if (k0 + j >= N_TOK) bits |= 1u << j;
    }
    pmT[(size_t)kt * QPAD + q] = bits;
}

// ---------------------------------------------------------------------------
// Kernel 2: fused (img + pos) -> token embed -> {Q | K,V} projection, bf16 out.
// Q,K: [head][token(TPAD)][32] bf16 (Q pre-scaled by 2^-4 * log2(e)).
// V: transposed [head][32][VTP] bf16.
// ---------------------------------------------------------------------------
__global__ __launch_bounds__(256) void embed_qkv_kernel(
    const float* __restrict__ x, const float* __restrict__ ctx,
    const float* __restrict__ row_embed, const float* __restrict__ col_embed,
    const float* __restrict__ w_in, const float* __restrict__ b_in,
    const float* __restrict__ wq, const float* __restrict__ bq,
    const float* __restrict__ wk, const float* __restrict__ bk,
    const float* __restrict__ wv, const float* __restrict__ bv,
    unsigned short* __restrict__ Qb, unsigned short* __restrict__ Kb,
    unsigned short* __restrict__ Vt)
{
    __shared__ __align__(16) float ysh[PIX][EMB_D];
    __shared__ __align__(16) float tsh[PIX][EMB_D];
    const int t  = threadIdx.x;
    const int n0 = blockIdx.x * PIX;
    const int which = blockIdx.y;
    const float* img = which ? ctx : x;
    const float QSCALE = 0.0625f * 1.4426950408889634f;

    {   // phase 1: y = img + pos
        const int c = t;
        float4 v0 = *(const float4*)(img + c * N_TOK + n0);
        float4 v1 = *(const float4*)(img + c * N_TOK + n0 + 4);
        float vv[8] = {v0.x, v0.y, v0.z, v0.w, v1.x, v1.y, v1.z, v1.w};
        #pragma unroll
        for (int p = 0; p < PIX; ++p) {
            int n  = n0 + p;
            int hh = n / W_DIM;
            int ww = n - hh * W_DIM;
            float pos = (c < 128) ? col_embed[ww * 128 + c]
                                  : row_embed[hh * 128 + (c - 128)];
            ysh[p][c] = vv[p] + pos;
        }
    }
    __syncthreads();

    {   // phase 2: token embed
        const int e = t;
        float acc[PIX];
        #pragma unroll
        for (int p = 0; p < PIX; ++p) acc[p] = 0.f;
        for (int c = 0; c < EMB_D; c += 4) {
            float4 w4 = *(const float4*)(w_in + e * EMB_D + c);
            #pragma unroll
            for (int p = 0; p < PIX; ++p) {
                float4 y4 = *(const float4*)&ysh[p][c];
                acc[p] += w4.x * y4.x + w4.y * y4.y + w4.z * y4.z + w4.w * y4.w;
            }
        }
        float bb = b_in[e];
        #pragma unroll
        for (int p = 0; p < PIX; ++p) tsh[p][e] = acc[p] + bb;
    }
    __syncthreads();

    {   // phase 3: Q or K,V projection
        const int e = t;
        const int head = e >> 5, d = e & 31;
        const int nm = which ? 2 : 1;
        for (int mi = 0; mi < nm; ++mi) {
            const float* wm = which ? (mi ? wv : wk) : wq;
            const float* bb_ = which ? (mi ? bv : bk) : bq;
            float acc[PIX];
            #pragma unroll
            for (int p = 0; p < PIX; ++p) acc[p] = 0.f;
            for (int c = 0; c < EMB_D; c += 4) {
                float4 w4 = *(const float4*)(wm + e * EMB_D + c);
                #pragma unroll
                for (int p = 0; p < PIX; ++p) {
                    float4 y4 = *(const float4*)&tsh[p][c];
                    acc[p] += w4.x * y4.x + w4.y * y4.y + w4.z * y4.z + w4.w * y4.w;
                }
            }
            float bbv = bb_[e];
            if (which && mi == 1) {
                // V: transposed row e = head*32+d, tokens n0..n0+7 contiguous
                union { unsigned u[4]; short8_t v; } pk;
                #pragma unroll
                for (int p2 = 0; p2 < 4; ++p2)
                    pk.u[p2] = pack2bf(acc[2 * p2] + bbv, acc[2 * p2 + 1] + bbv);
                *(short8_t*)(Vt + (size_t)e * VTP + n0) = pk.v;
            } else {
                unsigned short* dst = (which ? Kb : Qb);
                const float sc = which ? 1.f : QSCALE;
                #pragma unroll
                for (int p = 0; p < PIX; ++p)
                    dst[(size_t)head * TPAD * 32 + (size_t)(n0 + p) * 32 + d] =
                        (unsigned short)f2bf((acc[p] + bbv) * sc);
            }
        }
    }
}

// ---------------------------------------------------------------------------
// Kernel 3: MFMA flash attention, no-max softmax (logits bounded ~|2.5|).
// Block = 4 waves = 1 qtile x 4 ksplits. Wave: 32 queries x 1 head.
// Swapped QK^T (S^T), O^T = V^T . P^T.  head = bid&7 (XCD locality).
// ---------------------------------------------------------------------------
__global__ __launch_bounds__(256) void attn_mfma_kernel(
    const unsigned short* __restrict__ Qb, const unsigned short* __restrict__ Kb,
    const unsigned short* __restrict__ Vt, const unsigned* __restrict__ pmT,
    float* __restrict__ AO)
{
    __shared__ float comb[3][17][64];

    const int t    = threadIdx.x;
    const int lane = t & 63;
    const int ks   = t >> 6;
    const int bid  = blockIdx.x;
    const int head = bid & 7;
    const int q0   = (bid >> 3) * 32;
    const int l31  = lane & 31;
    const int h    = lane >> 5;
    const int grp8 = h * 8;

    const unsigned short* Kh = Kb + (size_t)head * TPAD * 32;
    const unsigned short* Qh = Qb + (size_t)head * TPAD * 32;
    const unsigned short* Vh = Vt + ((size_t)head * 32 + l31) * VTP;

    short8_t qf0 = *(const short8_t*)(Qh + (size_t)(q0 + l31) * 32 + grp8);
    short8_t qf1 = *(const short8_t*)(Qh + (size_t)(q0 + l31) * 32 + 16 + grp8);

    f32x16 oacc;
    #pragma unroll
    for (int r = 0; r < 16; ++r) oacc[r] = 0.f;
    float lsum = 0.f;

    const int kt0 = ks ? ks * 39 + 1 : 0;     // 0,40,79,118
    const int kt1 = (ks + 1) * 39 + 1;        // 40,79,118,157

    short8_t ka0, ka1, va0, va1; unsigned mw;
    {   // preload first tile
        int k0 = kt0 * 32;
        const unsigned short* kp = Kh + (size_t)(k0 + l31) * 32 + grp8;
        ka0 = *(const short8_t*)kp;
        ka1 = *(const short8_t*)(kp + 16);
        va0 = *(const short8_t*)(Vh + k0 + grp8);
        va1 = *(const short8_t*)(Vh + k0 + 16 + grp8);
        mw  = pmT[(size_t)kt0 * QPAD + q0 + l31];
    }

    for (int kt = kt0; kt < kt1; ++kt) {
        // prefetch next tile (clamped)
        int ktn = (kt + 1 < kt1) ? kt + 1 : kt;
        int k0n = ktn * 32;
        const unsigned short* kpn = Kh + (size_t)(k0n + l31) * 32 + grp8;
        short8_t nka0 = *(const short8_t*)kpn;
        short8_t nka1 = *(const short8_t*)(kpn + 16);
        short8_t nva0 = *(const short8_t*)(Vh + k0n + grp8);
        short8_t nva1 = *(const short8_t*)(Vh + k0n + 16 + grp8);
        unsigned nmw  = pmT[(size_t)ktn * QPAD + q0 + l31];

        // S^T = K . Q^T (rows: keys, cols: queries); Q carries scale*log2e
        f32x16 sacc;
        #pragma unroll
        for (int r = 0; r < 16; ++r) sacc[r] = 0.f;
        sacc = __builtin_amdgcn_mfma_f32_32x32x16_bf16(ka0, qf0, sacc, 0, 0, 0);
        sacc = __builtin_amdgcn_mfma_f32_32x32x16_bf16(ka1, qf1, sacc, 0, 0, 0);

        unsigned wga[4];
        wga[0] = mw >> (4 * h);      wga[1] = mw >> (8 + 4 * h);
        wga[2] = mw >> (16 + 4 * h); wga[3] = mw >> (24 + 4 * h);

        float pf[16];
        #pragma unroll
        for (int r = 0; r < 16; ++r) {
            float p = exp2f(sacc[r]);                       // v_exp_f32
            p = ((wga[r >> 2] >> (r & 3)) & 1u) ? 0.f : p;  // mask -> exact 0
            pf[r] = p;
            lsum += p;
        }

        // build P^T B-frags and accumulate O^T
        const int oo = 4 * h, oe = 4 - 4 * h;
        #pragma unroll
        for (int c = 0; c < 2; ++c) {
            const int base = 8 * c;
            unsigned own0 = pack2bf(pf[base + oo + 0], pf[base + oo + 1]);
            unsigned own1 = pack2bf(pf[base + oo + 2], pf[base + oo + 3]);
            unsigned e0   = pack2bf(pf[base + oe + 0], pf[base + oe + 1]);
            unsigned e1   = pack2bf(pf[base + oe + 2], pf[base + oe + 3]);
            unsigned r0 = (unsigned)__shfl_xor((int)e0, 32);
            unsigned r1 = (unsigned)__shfl_xor((int)e1, 32);
            union { unsigned u[4]; short8_t v; } fr;
            fr.u[0] = h ? r0 : own0;
            fr.u[1] = h ? r1 : own1;
            fr.u[2] = h ? own0 : r0;
            fr.u[3] = h ? own1 : r1;
            oacc = __builtin_amdgcn_mfma_f32_32x32x16_bf16(c ? va1 : va0, fr.v, oacc, 0, 0, 0);
        }

        ka0 = nka0; ka1 = nka1; va0 = nva0; va1 = nva1; mw = nmw;
    }

    float lfull = lsum + __shfl_xor(lsum, 32);

    if (ks) {
        comb[ks - 1][0][lane] = lfull;
        #pragma unroll
        for (int r = 0; r < 16; ++r) comb[ks - 1][1 + r][lane] = oacc[r];
    }
    __syncthreads();
    if (ks == 0) {
        float den = lfull + comb[0][0][lane] + comb[1][0][lane] + comb[2][0][lane];
        float inv = 1.f / den;
        int q = q0 + l31;
        if (q < N_TOK) {
            #pragma unroll
            for (int u = 0; u < 4; ++u) {
                float4 vv;
                #pragma unroll
                for (int j = 0; j < 4; ++j) {
                    int r = 4 * u + j;
                    float o = oacc[r] + comb[0][1 + r][lane] + comb[1][1 + r][lane]
                                      + comb[2][1 + r][lane];
                    (&vv.x)[j] = o * inv;
                }
                *(float4*)(AO + (size_t)q * EMB_D + head * 32 + 8 * u + 4 * h) = vv;
            }
        }
    }
}

// ---------------------------------------------------------------------------
// Kernel 4: output projection out[c,n] = b_out[c] + sum_e w_out[c][e]*AO[n][e]
// ---------------------------------------------------------------------------
__global__ __launch_bounds__(256) void proj_out_kernel(
    const float* __restrict__ AO, const float* __restrict__ w_out,
    const float* __restrict__ b_out, float* __restrict__ out)
{
    __shared__ __align__(16) float a[PIX][EMB_D];
    const int t  = threadIdx.x;
    const int n0 = blockIdx.x * PIX;
    #pragma unroll
    for (int i = 0; i < 2; ++i) {
        int f = t + 256 * i;        // 512 float4 = 8 pixels x 64 float4
        int p = f >> 6, e4 = f & 63;
        *(float4*)&a[p][e4 * 4] = *(const float4*)(AO + (size_t)(n0 + p) * EMB_D + e4 * 4);
    }
    __syncthreads();

    const int c = t;
    float acc[PIX];
    #pragma unroll
    for (int p = 0; p < PIX; ++p) acc[p] = 0.f;
    for (int e = 0; e < EMB_D; e += 4) {
        float4 w4 = *(const float4*)(w_out + c * EMB_D + e);
        #pragma unroll
        for (int p = 0; p < PIX; ++p) {
            float4 a4 = *(const float4*)&a[p][e];
            acc[p] += w4.x * a4.x + w4.y * a4.y + w4.z * a4.z + w4.w * a4.w;
        }
    }
    float bb = b_out[c];
    float4 r0, r1;
    r0.x = acc[0] + bb; r0.y = acc[1] + bb; r0.z = acc[2] + bb; r0.w = acc[3] + bb;
    r1.x = acc[4] + bb; r1.y = acc[5] + bb; r1.z = acc[6] + bb; r1.w = acc[7] + bb;
    *(float4*)(out + (size_t)c * N_TOK + n0)     = r0;
    *(float4*)(out + (size_t)c * N_TOK + n0 + 4) = r1;
}

// ---------------------------------------------------------------------------
extern "C" void kernel_launch(void* const* d_in, const int* in_sizes, int n_in,
                              void* d_out, int out_size, void* d_ws, size_t ws_size,
                              hipStream_t stream) {
    const float* x         = (const float*)d_in[0];
    const float* ctx       = (const float*)d_in[1];
    const void*  mask      = (const void*) d_in[2];
    const float* row_embed = (const float*)d_in[3];
    const float* col_embed = (const float*)d_in[4];
    const float* w_in      = (const float*)d_in[5];
    const float* b_in      = (const float*)d_in[6];
    const float* wq        = (const float*)d_in[7];
    const float* bq        = (const float*)d_in[8];
    const float* wk        = (const float*)d_in[9];
    const float* bk        = (const float*)d_in[10];
    const float* wv        = (const float*)d_in[11];
    const float* bv        = (const float*)d_in[12];
    const float* w_out     = (const float*)d_in[13];
    const float* b_out     = (const float*)d_in[14];
    float* out = (float*)d_out;

    char* ws = (char*)d_ws;
    unsigned short* Qb  = (unsigned short*)(ws);                    // 2,588,672 B
    unsigned short* Kb  = (unsigned short*)(ws + 2588672);          // 2,588,672 B
    unsigned short* Vt  = (unsigned short*)(ws + 5177344);          // 2,621,440 B
    unsigned*       pmT = (unsigned*)      (ws + 7798784);          // 3,175,168 B
    float*          AO  = (float*)         (ws + 10973952);         // 5,120,000 B
    int*       maskflag = (int*)           (ws + 16093952);

    detect_mask_kernel<<<1, 64, 0, stream>>>((const unsigned*)mask, maskflag);
    pack_mask_kernel<<<dim3(20, NKT), 256, 0, stream>>>(mask, maskflag, pmT);
    embed_qkv_kernel<<<dim3(625, 2), 256, 0, stream>>>(
        x, ctx, row_embed, col_embed, w_in, b_in, wq, bq, wk, bk, wv, bv, Qb, Kb, Vt);
    attn_mfma_kernel<<<dim3(157 * 8), 256, 0, stream>>>(Qb, Kb, Vt, pmT, AO);
    proj_out_kernel<<<dim3(625), 256, 0, stream>>>(AO, w_out, b_out, out);
}

// Round 5
// 245.263 us; speedup vs baseline: 9.4053x; 1.6812x over previous
//
#include <hip/hip_runtime.h>
#include <hip/hip_bf16.h>
#include <math.h>

#define N_TOK 5000
#define EMB_D 256
#define HEADS 8
#define DEPTH 32
#define W_DIM 100
#define PIX 8
#define TPAD 5120
#define VTP  5120
#define QPAD 5056
#define NKT  157
#define NKT_PAD 160

typedef __attribute__((ext_vector_type(8)))  short short8_t;
typedef __attribute__((ext_vector_type(16))) float f32x16;
typedef __attribute__((ext_vector_type(2)))  unsigned uint2v;

__device__ __forceinline__ unsigned f2bf(float x) {
    union { float f; unsigned u; } c; c.f = x;
    return (c.u + 0x8000u) >> 16;
}
__device__ __forceinline__ unsigned pack2bf(float lo, float hi) {
    __hip_bfloat162 h2 = __float22bfloat162_rn(make_float2(lo, hi));
    union { __hip_bfloat162 h; unsigned u; } c; c.h = h2;
    return c.u;
}

// ---------------------------------------------------------------------------
// Kernel 0: detect mask dtype (word 0/1/1.0f vs packed bytes). 1 wave.
// ---------------------------------------------------------------------------
__global__ void detect_mask_kernel(const unsigned* __restrict__ mask,
                                   int* __restrict__ flag) {
    int t = threadIdx.x;
    bool bad = false;
    for (int i = 0; i < 16; ++i) {
        unsigned w = mask[t * 16 + i];
        if (w != 0u && w != 1u && w != 0x3F800000u) bad = true;
    }
    unsigned long long bb = __ballot(bad);
    if (t == 0) *flag = (bb != 0ull) ? 1 : 0;
}

// ---------------------------------------------------------------------------
// Kernel 1: pack mask to bits, transposed: pmT[kt][q] bit j = masked(q, kt*32+j)
// kt in [157,160) -> all-masked (padding tiles).
// ---------------------------------------------------------------------------
__global__ __launch_bounds__(256) void pack_mask_kernel(
    const void* __restrict__ mask_raw, const int* __restrict__ flag,
    unsigned* __restrict__ pmT)
{
    int q  = blockIdx.x * 256 + threadIdx.x;
    int kt = blockIdx.y;
    if (q >= N_TOK) return;
    int k0 = kt * 32;
    if (k0 >= N_TOK) {                       // padding tile: fully masked
        pmT[(size_t)kt * QPAD + q] = 0xFFFFFFFFu;
        return;
    }
    unsigned bits = 0;
    if (*flag) {  // byte mask
        const unsigned* src = (const unsigned*)((const char*)mask_raw + ((size_t)q * N_TOK + k0));
        #pragma unroll
        for (int w = 0; w < 8; ++w) {
            unsigned u = src[w];
            #pragma unroll
            for (int b = 0; b < 4; ++b)
                if (u & (0xFFu << (8 * b))) bits |= 1u << (4 * w + b);
        }
    } else {      // int32 mask
        const int4* src = (const int4*)((const int*)mask_raw + (size_t)q * N_TOK + k0);
        #pragma unroll
        for (int w = 0; w < 8; ++w) {
            int4 u = src[w];
            if (u.x) bits |= 1u << (4 * w + 0);
            if (u.y) bits |= 1u << (4 * w + 1);
            if (u.z) bits |= 1u << (4 * w + 2);
            if (u.w) bits |= 1u << (4 * w + 3);
        }
    }
    if (k0 + 32 > N_TOK) {
        #pragma unroll
        for (int j = 0; j < 32; ++j)
            if (k0 + j >= N_TOK) bits |= 1u << j;
    }
    pmT[(size_t)kt * QPAD + q] = bits;
}

// ---------------------------------------------------------------------------
// Kernel 2: fused (img + pos) -> token embed -> {Q | K,V} projection, bf16 out.
// Q,K: [head][token(TPAD)][32] bf16 (Q pre-scaled by 2^-4 * log2(e)).
// V: transposed [head][32][VTP] bf16.
// ---------------------------------------------------------------------------
__global__ __launch_bounds__(256) void embed_qkv_kernel(
    const float* __restrict__ x, const float* __restrict__ ctx,
    const float* __restrict__ row_embed, const float* __restrict__ col_embed,
    const float* __restrict__ w_in, const float* __restrict__ b_in,
    const float* __restrict__ wq, const float* __restrict__ bq,
    const float* __restrict__ wk, const float* __restrict__ bk,
    const float* __restrict__ wv, const float* __restrict__ bv,
    unsigned short* __restrict__ Qb, unsigned short* __restrict__ Kb,
    unsigned short* __restrict__ Vt)
{
    __shared__ __align__(16) float ysh[PIX][EMB_D];
    __shared__ __align__(16) float tsh[PIX][EMB_D];
    const int t  = threadIdx.x;
    const int n0 = blockIdx.x * PIX;
    const int which = blockIdx.y;
    const float* img = which ? ctx : x;
    const float QSCALE = 0.0625f * 1.4426950408889634f;

    {   // phase 1: y = img + pos
        const int c = t;
        float4 v0 = *(const float4*)(img + c * N_TOK + n0);
        float4 v1 = *(const float4*)(img + c * N_TOK + n0 + 4);
        float vv[8] = {v0.x, v0.y, v0.z, v0.w, v1.x, v1.y, v1.z, v1.w};
        #pragma unroll
        for (int p = 0; p < PIX; ++p) {
            int n  = n0 + p;
            int hh = n / W_DIM;
            int ww = n - hh * W_DIM;
            float pos = (c < 128) ? col_embed[ww * 128 + c]
                                  : row_embed[hh * 128 + (c - 128)];
            ysh[p][c] = vv[p] + pos;
        }
    }
    __syncthreads();

    {   // phase 2: token embed
        const int e = t;
        float acc[PIX];
        #pragma unroll
        for (int p = 0; p < PIX; ++p) acc[p] = 0.f;
        for (int c = 0; c < EMB_D; c += 4) {
            float4 w4 = *(const float4*)(w_in + e * EMB_D + c);
            #pragma unroll
            for (int p = 0; p < PIX; ++p) {
                float4 y4 = *(const float4*)&ysh[p][c];
                acc[p] += w4.x * y4.x + w4.y * y4.y + w4.z * y4.z + w4.w * y4.w;
            }
        }
        float bb = b_in[e];
        #pragma unroll
        for (int p = 0; p < PIX; ++p) tsh[p][e] = acc[p] + bb;
    }
    __syncthreads();

    {   // phase 3: Q or K,V projection
        const int e = t;
        const int head = e >> 5, d = e & 31;
        const int nm = which ? 2 : 1;
        for (int mi = 0; mi < nm; ++mi) {
            const float* wm = which ? (mi ? wv : wk) : wq;
            const float* bb_ = which ? (mi ? bv : bk) : bq;
            float acc[PIX];
            #pragma unroll
            for (int p = 0; p < PIX; ++p) acc[p] = 0.f;
            for (int c = 0; c < EMB_D; c += 4) {
                float4 w4 = *(const float4*)(wm + e * EMB_D + c);
                #pragma unroll
                for (int p = 0; p < PIX; ++p) {
                    float4 y4 = *(const float4*)&tsh[p][c];
                    acc[p] += w4.x * y4.x + w4.y * y4.y + w4.z * y4.z + w4.w * y4.w;
                }
            }
            float bbv = bb_[e];
            if (which && mi == 1) {
                // V: transposed row e = head*32+d, tokens n0..n0+7 contiguous
                union { unsigned u[4]; short8_t v; } pk;
                #pragma unroll
                for (int p2 = 0; p2 < 4; ++p2)
                    pk.u[p2] = pack2bf(acc[2 * p2] + bbv, acc[2 * p2 + 1] + bbv);
                *(short8_t*)(Vt + (size_t)e * VTP + n0) = pk.v;
            } else {
                unsigned short* dst = (which ? Kb : Qb);
                const float sc = which ? 1.f : QSCALE;
                #pragma unroll
                for (int p = 0; p < PIX; ++p)
                    dst[(size_t)head * TPAD * 32 + (size_t)(n0 + p) * 32 + d] =
                        (unsigned short)f2bf((acc[p] + bbv) * sc);
            }
        }
    }
}

// ---------------------------------------------------------------------------
// Kernel 3: MFMA flash attention, no-max softmax. Block = 8 waves = 1 qtile x
// 8 ksplits of 20 tiles each (k-space padded to 160 tiles; pads fully masked).
// Wave: 32 queries x 1 head. Swapped QK^T (S^T), O^T = V^T . P^T.
// head = bid&7 (XCD L2 locality). P-frag halves exchanged via permlane32_swap.
// ---------------------------------------------------------------------------
__global__ __launch_bounds__(512) void attn_mfma_kernel(
    const unsigned short* __restrict__ Qb, const unsigned short* __restrict__ Kb,
    const unsigned short* __restrict__ Vt, const unsigned* __restrict__ pmT,
    float* __restrict__ AO)
{
    __shared__ float comb[7][17][64];

    const int t    = threadIdx.x;
    const int lane = t & 63;
    const int ks   = t >> 6;                 // 0..7: k-split
    const int bid  = blockIdx.x;
    const int head = bid & 7;
    const int q0   = (bid >> 3) * 32;
    const int l31  = lane & 31;
    const int h    = lane >> 5;
    const int grp8 = h * 8;

    const unsigned short* Kh = Kb + (size_t)head * TPAD * 32;
    const unsigned short* Qh = Qb + (size_t)head * TPAD * 32;
    const unsigned short* Vh = Vt + ((size_t)head * 32 + l31) * VTP;

    short8_t qf0 = *(const short8_t*)(Qh + (size_t)(q0 + l31) * 32 + grp8);
    short8_t qf1 = *(const short8_t*)(Qh + (size_t)(q0 + l31) * 32 + 16 + grp8);

    f32x16 oacc;
    #pragma unroll
    for (int r = 0; r < 16; ++r) oacc[r] = 0.f;
    float lsum = 0.f;

    const int kt0 = ks * 20;

    short8_t ka0, ka1, va0, va1; unsigned mw;
    {   // preload first tile
        int k0 = kt0 * 32;
        const unsigned short* kp = Kh + (size_t)(k0 + l31) * 32 + grp8;
        ka0 = *(const short8_t*)kp;
        ka1 = *(const short8_t*)(kp + 16);
        va0 = *(const short8_t*)(Vh + k0 + grp8);
        va1 = *(const short8_t*)(Vh + k0 + 16 + grp8);
        mw  = pmT[(size_t)kt0 * QPAD + q0 + l31];
    }

    #pragma unroll 2
    for (int it = 0; it < 20; ++it) {
        // prefetch next tile (clamped on last)
        int itn = (it < 19) ? it + 1 : it;
        int k0n = (kt0 + itn) * 32;
        const unsigned short* kpn = Kh + (size_t)(k0n + l31) * 32 + grp8;
        short8_t nka0 = *(const short8_t*)kpn;
        short8_t nka1 = *(const short8_t*)(kpn + 16);
        short8_t nva0 = *(const short8_t*)(Vh + k0n + grp8);
        short8_t nva1 = *(const short8_t*)(Vh + k0n + 16 + grp8);
        unsigned nmw  = pmT[(size_t)(kt0 + itn) * QPAD + q0 + l31];

        // S^T = K . Q^T (rows: keys, cols: queries); Q carries scale*log2e
        f32x16 sacc;
        #pragma unroll
        for (int r = 0; r < 16; ++r) sacc[r] = 0.f;
        sacc = __builtin_amdgcn_mfma_f32_32x32x16_bf16(ka0, qf0, sacc, 0, 0, 0);
        sacc = __builtin_amdgcn_mfma_f32_32x32x16_bf16(ka1, qf1, sacc, 0, 0, 0);

        unsigned wga[4];
        wga[0] = mw >> (4 * h);      wga[1] = mw >> (8 + 4 * h);
        wga[2] = mw >> (16 + 4 * h); wga[3] = mw >> (24 + 4 * h);

        float p[16];
        #pragma unroll
        for (int r = 0; r < 16; ++r) {
            float e = __builtin_amdgcn_exp2f(sacc[r]);      // v_exp_f32
            p[r] = ((wga[r >> 2] >> (r & 3)) & 1u) ? 0.f : e;
        }
        // tree-sum (short dependency chain)
        {
            float s0 = (p[0] + p[1]) + (p[2] + p[3]);
            float s1 = (p[4] + p[5]) + (p[6] + p[7]);
            float s2 = (p[8] + p[9]) + (p[10] + p[11]);
            float s3 = (p[12] + p[13]) + (p[14] + p[15]);
            lsum += (s0 + s1) + (s2 + s3);
        }

        // build P^T B-frags via permlane32_swap and accumulate O^T
        #pragma unroll
        for (int c = 0; c < 2; ++c) {
            const int b = 8 * c;
            unsigned a0 = pack2bf(p[b + 0], p[b + 1]);
            unsigned b0 = pack2bf(p[b + 4], p[b + 5]);
            unsigned a1 = pack2bf(p[b + 2], p[b + 3]);
            unsigned b1 = pack2bf(p[b + 6], p[b + 7]);
            uint2v s02 = __builtin_amdgcn_permlane32_swap(a0, b0, false, false);
            uint2v s13 = __builtin_amdgcn_permlane32_swap(a1, b1, false, false);
            union { unsigned u[4]; short8_t v; } fr;
            fr.u[0] = s02.x;    // rows0-31: pack01(self) | rows32-63: pack45(partner)
            fr.u[1] = s13.x;
            fr.u[2] = s02.y;    // rows0-31: pack01(partner) | rows32-63: pack45(self)
            fr.u[3] = s13.y;
            oacc = __builtin_amdgcn_mfma_f32_32x32x16_bf16(c ? va1 : va0, fr.v, oacc, 0, 0, 0);
        }

        ka0 = nka0; ka1 = nka1; va0 = nva0; va1 = nva1; mw = nmw;
    }

    float lfull = lsum + __shfl_xor(lsum, 32);

    if (ks) {
        comb[ks - 1][0][lane] = lfull;
        #pragma unroll
        for (int r = 0; r < 16; ++r) comb[ks - 1][1 + r][lane] = oacc[r];
    }
    __syncthreads();
    if (ks == 0) {
        float den = lfull;
        #pragma unroll
        for (int s = 0; s < 7; ++s) den += comb[s][0][lane];
        float inv = 1.f / den;
        int q = q0 + l31;
        if (q < N_TOK) {
            #pragma unroll
            for (int u = 0; u < 4; ++u) {
                float4 vv;
                #pragma unroll
                for (int j = 0; j < 4; ++j) {
                    int r = 4 * u + j;
                    float o = oacc[r];
                    #pragma unroll
                    for (int s = 0; s < 7; ++s) o += comb[s][1 + r][lane];
                    (&vv.x)[j] = o * inv;
                }
                *(float4*)(AO + (size_t)q * EMB_D + head * 32 + 8 * u + 4 * h) = vv;
            }
        }
    }
}

// ---------------------------------------------------------------------------
// Kernel 4: output projection out[c,n] = b_out[c] + sum_e w_out[c][e]*AO[n][e]
// ---------------------------------------------------------------------------
__global__ __launch_bounds__(256) void proj_out_kernel(
    const float* __restrict__ AO, const float* __restrict__ w_out,
    const float* __restrict__ b_out, float* __restrict__ out)
{
    __shared__ __align__(16) float a[PIX][EMB_D];
    const int t  = threadIdx.x;
    const int n0 = blockIdx.x * PIX;
    #pragma unroll
    for (int i = 0; i < 2; ++i) {
        int f = t + 256 * i;        // 512 float4 = 8 pixels x 64 float4
        int p = f >> 6, e4 = f & 63;
        *(float4*)&a[p][e4 * 4] = *(const float4*)(AO + (size_t)(n0 + p) * EMB_D + e4 * 4);
    }
    __syncthreads();

    const int c = t;
    float acc[PIX];
    #pragma unroll
    for (int p = 0; p < PIX; ++p) acc[p] = 0.f;
    for (int e = 0; e < EMB_D; e += 4) {
        float4 w4 = *(const float4*)(w_out + c * EMB_D + e);
        #pragma unroll
        for (int p = 0; p < PIX; ++p) {
            float4 a4 = *(const float4*)&a[p][e];
            acc[p] += w4.x * a4.x + w4.y * a4.y + w4.z * a4.z + w4.w * a4.w;
        }
    }
    float bb = b_out[c];
    float4 r0, r1;
    r0.x = acc[0] + bb; r0.y = acc[1] + bb; r0.z = acc[2] + bb; r0.w = acc[3] + bb;
    r1.x = acc[4] + bb; r1.y = acc[5] + bb; r1.z = acc[6] + bb; r1.w = acc[7] + bb;
    *(float4*)(out + (size_t)c * N_TOK + n0)     = r0;
    *(float4*)(out + (size_t)c * N_TOK + n0 + 4) = r1;
}

// ---------------------------------------------------------------------------
extern "C" void kernel_launch(void* const* d_in, const int* in_sizes, int n_in,
                              void* d_out, int out_size, void* d_ws, size_t ws_size,
                              hipStream_t stream) {
    const float* x         = (const float*)d_in[0];
    const float* ctx       = (const float*)d_in[1];
    const void*  mask      = (const void*) d_in[2];
    const float* row_embed = (const float*)d_in[3];
    const float* col_embed = (const float*)d_in[4];
    const float* w_in      = (const float*)d_in[5];
    const float* b_in      = (const float*)d_in[6];
    const float* wq        = (const float*)d_in[7];
    const float* bq        = (const float*)d_in[8];
    const float* wk        = (const float*)d_in[9];
    const float* bk        = (const float*)d_in[10];
    const float* wv        = (const float*)d_in[11];
    const float* bv        = (const float*)d_in[12];
    const float* w_out     = (const float*)d_in[13];
    const float* b_out     = (const float*)d_in[14];
    float* out = (float*)d_out;

    char* ws = (char*)d_ws;
    unsigned short* Qb  = (unsigned short*)(ws);                    // 2,621,440 B
    unsigned short* Kb  = (unsigned short*)(ws + 2621440);          // 2,621,440 B
    unsigned short* Vt  = (unsigned short*)(ws + 5242880);          // 2,621,440 B
    unsigned*       pmT = (unsigned*)      (ws + 7864320);          // 3,235,840 B
    float*          AO  = (float*)         (ws + 11100160);         // 5,120,000 B
    int*       maskflag = (int*)           (ws + 16220160);

    detect_mask_kernel<<<1, 64, 0, stream>>>((const unsigned*)mask, maskflag);
    pack_mask_kernel<<<dim3(20, NKT_PAD), 256, 0, stream>>>(mask, maskflag, pmT);
    embed_qkv_kernel<<<dim3(625, 2), 256, 0, stream>>>(
        x, ctx, row_embed, col_embed, w_in, b_in, wq, bq, wk, bk, wv, bv, Qb, Kb, Vt);
    attn_mfma_kernel<<<dim3(157 * 8), 512, 0, stream>>>(Qb, Kb, Vt, pmT, AO);
    proj_out_kernel<<<dim3(625), 256, 0, stream>>>(AO, w_out, b_out, out);
}

// Round 6
// 214.888 us; speedup vs baseline: 10.7348x; 1.1414x over previous
//
#include <hip/hip_runtime.h>
#include <hip/hip_bf16.h>
#include <math.h>

#define N_TOK 5000
#define EMB_D 256
#define W_DIM 100
#define TPAD 5120
#define VTP  5120
#define QPAD 5056
#define NKT  157
#define NKT_PAD 160

typedef __attribute__((ext_vector_type(8)))  short short8_t;
typedef __attribute__((ext_vector_type(16))) float f32x16;
typedef __attribute__((ext_vector_type(2)))  unsigned uint2v;

__device__ __forceinline__ unsigned f2bf(float x) {
    union { float f; unsigned u; } c; c.f = x;
    return (c.u + 0x8000u) >> 16;
}
__device__ __forceinline__ unsigned pack2bf(float lo, float hi) {
    __hip_bfloat162 h2 = __float22bfloat162_rn(make_float2(lo, hi));
    union { __hip_bfloat162 h; unsigned u; } c; c.h = h2;
    return c.u;
}
// C[rows via crow(r,h)][cols via l31] -> bf16 operand frag for 16-row block cb:
// lane holds rows cb*16 + 8h..8h+7 (contiguous bf16), col = l31.
// Verified mapping (rounds 3-5 attention P-build).
__device__ __forceinline__ short8_t mkfrag(const f32x16& c, int cb) {
    const int b = 8 * cb;
    unsigned a0 = pack2bf(c[b + 0], c[b + 1]);
    unsigned a1 = pack2bf(c[b + 2], c[b + 3]);
    unsigned b0 = pack2bf(c[b + 4], c[b + 5]);
    unsigned b1 = pack2bf(c[b + 6], c[b + 7]);
    uint2v s02 = __builtin_amdgcn_permlane32_swap(a0, b0, false, false);
    uint2v s13 = __builtin_amdgcn_permlane32_swap(a1, b1, false, false);
    union { unsigned u[4]; short8_t v; } fr;
    fr.u[0] = s02.x; fr.u[1] = s13.x; fr.u[2] = s02.y; fr.u[3] = s13.y;
    return fr.v;
}

// ---------------------------------------------------------------------------
// Kernel 0: detect mask dtype (word 0/1/1.0f vs packed bytes). 1 wave.
// ---------------------------------------------------------------------------
__global__ void detect_mask_kernel(const unsigned* __restrict__ mask,
                                   int* __restrict__ flag) {
    int t = threadIdx.x;
    bool bad = false;
    for (int i = 0; i < 16; ++i) {
        unsigned w = mask[t * 16 + i];
        if (w != 0u && w != 1u && w != 0x3F800000u) bad = true;
    }
    unsigned long long bb = __ballot(bad);
    if (t == 0) *flag = (bb != 0ull) ? 1 : 0;
}

// ---------------------------------------------------------------------------
// Kernel 1: pack mask to bits, transposed: pmT[kt][q] bit j = masked(q, kt*32+j)
// kt in [157,160) -> all-masked (padding tiles).
// ---------------------------------------------------------------------------
__global__ __launch_bounds__(256) void pack_mask_kernel(
    const void* __restrict__ mask_raw, const int* __restrict__ flag,
    unsigned* __restrict__ pmT)
{
    int q  = blockIdx.x * 256 + threadIdx.x;
    int kt = blockIdx.y;
    if (q >= N_TOK) return;
    int k0 = kt * 32;
    if (k0 >= N_TOK) {
        pmT[(size_t)kt * QPAD + q] = 0xFFFFFFFFu;
        return;
    }
    unsigned bits = 0;
    if (*flag) {  // byte mask
        const unsigned* src = (const unsigned*)((const char*)mask_raw + ((size_t)q * N_TOK + k0));
        #pragma unroll
        for (int w = 0; w < 8; ++w) {
            unsigned u = src[w];
            #pragma unroll
            for (int b = 0; b < 4; ++b)
                if (u & (0xFFu << (8 * b))) bits |= 1u << (4 * w + b);
        }
    } else {      // int32 mask
        const int4* src = (const int4*)((const int*)mask_raw + (size_t)q * N_TOK + k0);
        #pragma unroll
        for (int w = 0; w < 8; ++w) {
            int4 u = src[w];
            if (u.x) bits |= 1u << (4 * w + 0);
            if (u.y) bits |= 1u << (4 * w + 1);
            if (u.z) bits |= 1u << (4 * w + 2);
            if (u.w) bits |= 1u << (4 * w + 3);
        }
    }
    if (k0 + 32 > N_TOK) {
        #pragma unroll
        for (int j = 0; j < 32; ++j)
            if (k0 + j >= N_TOK) bits |= 1u << j;
    }
    pmT[(size_t)kt * QPAD + q] = bits;
}

// ---------------------------------------------------------------------------
// Kernel 2: convert the 5 weight matrices (256x256 f32) to bf16. grid (64,5).
// Wb layout: [w_in | wq | wk | wv | w_out], each 65536 bf16.
// ---------------------------------------------------------------------------
__global__ __launch_bounds__(256) void wb16_kernel(
    const float* __restrict__ w_in, const float* __restrict__ wq,
    const float* __restrict__ wk, const float* __restrict__ wv,
    const float* __restrict__ w_out, unsigned short* __restrict__ Wb)
{
    const float* srcs[5] = {w_in, wq, wk, wv, w_out};
    const float* s = srcs[blockIdx.y];
    unsigned short* d = Wb + (size_t)blockIdx.y * 65536;
    int i = (blockIdx.x * 256 + threadIdx.x) * 4;
    float4 v = *(const float4*)(s + i);
    uint2 u;
    u.x = pack2bf(v.x, v.y);
    u.y = pack2bf(v.z, v.w);
    *(uint2*)&d[i] = u;
}

// ---------------------------------------------------------------------------
// GEMM2 helpers (inlined in embed kernel)
// ---------------------------------------------------------------------------
__device__ __forceinline__ void gemm2_rowmajor(
    const short8_t* tokfr, const unsigned short* __restrict__ W,
    const float* __restrict__ bias, float sc,
    unsigned short* __restrict__ dst, int tok, int l31, int h)
{
    const int chb = 8 * h;
    #pragma unroll
    for (int ot = 0; ot < 8; ++ot) {
        f32x16 c;
        #pragma unroll
        for (int r = 0; r < 16; ++r) c[r] = 0.f;
        #pragma unroll
        for (int blk = 0; blk < 16; ++blk) {
            short8_t wf = *(const short8_t*)(W + (size_t)(ot * 32 + l31) * 256 + blk * 16 + chb);
            c = __builtin_amdgcn_mfma_f32_32x32x16_bf16(wf, tokfr[blk], c, 0, 0, 0);
        }
        #pragma unroll
        for (int m = 0; m < 4; ++m) {
            float4 b4 = *(const float4*)(bias + ot * 32 + 4 * h + 8 * m);
            c[4 * m + 0] = (c[4 * m + 0] + b4.x) * sc;
            c[4 * m + 1] = (c[4 * m + 1] + b4.y) * sc;
            c[4 * m + 2] = (c[4 * m + 2] + b4.z) * sc;
            c[4 * m + 3] = (c[4 * m + 3] + b4.w) * sc;
        }
        short8_t f0 = mkfrag(c, 0), f1 = mkfrag(c, 1);
        *(short8_t*)(dst + (size_t)ot * TPAD * 32 + (size_t)tok * 32 + chb)      = f0;
        *(short8_t*)(dst + (size_t)ot * TPAD * 32 + (size_t)tok * 32 + 16 + chb) = f1;
    }
}

__device__ __forceinline__ void gemm2_vt(
    const short8_t* tokfr, const unsigned short* __restrict__ W,
    const float* __restrict__ bias,
    unsigned short* __restrict__ Vt, int tok, int l31, int h)
{
    const int chb = 8 * h;
    #pragma unroll
    for (int ot = 0; ot < 8; ++ot) {
        f32x16 c;
        #pragma unroll
        for (int r = 0; r < 16; ++r) c[r] = 0.f;
        #pragma unroll
        for (int blk = 0; blk < 16; ++blk) {
            short8_t wf = *(const short8_t*)(W + (size_t)(ot * 32 + l31) * 256 + blk * 16 + chb);
            c = __builtin_amdgcn_mfma_f32_32x32x16_bf16(wf, tokfr[blk], c, 0, 0, 0);
        }
        #pragma unroll
        for (int m = 0; m < 4; ++m) {
            float4 b4 = *(const float4*)(bias + ot * 32 + 4 * h + 8 * m);
            c[4 * m + 0] += b4.x; c[4 * m + 1] += b4.y;
            c[4 * m + 2] += b4.z; c[4 * m + 3] += b4.w;
        }
        #pragma unroll
        for (int r = 0; r < 16; ++r) {
            int vd = (r & 3) + 8 * (r >> 2) + 4 * h;
            Vt[(size_t)(ot * 32 + vd) * VTP + tok] = (unsigned short)f2bf(c[r]);
        }
    }
}

// ---------------------------------------------------------------------------
// Kernel 3: MFMA fused embed: y=img+pos -> tok=W_in.y+b (in-register bf16
// frags) -> {Q | K,V}. 1 wave / 32-token tile. grid (157, 2).
// ---------------------------------------------------------------------------
__global__ __launch_bounds__(64) void embed_qkv_kernel(
    const float* __restrict__ x, const float* __restrict__ ctx,
    const float* __restrict__ row_embed, const float* __restrict__ col_embed,
    const unsigned short* __restrict__ Wb,
    const float* __restrict__ b_in, const float* __restrict__ bq,
    const float* __restrict__ bk, const float* __restrict__ bv,
    unsigned short* __restrict__ Qb, unsigned short* __restrict__ Kb,
    unsigned short* __restrict__ Vt)
{
    const int lane = threadIdx.x;
    const int l31 = lane & 31, h = lane >> 5;
    const int chb = 8 * h;
    const int which = blockIdx.y;
    const int tok0 = blockIdx.x * 32;
    const int tok  = tok0 + l31;                  // <= 5023 < TPAD
    const int tokc = min(tok, N_TOK - 1);         // clamp loads
    const float* img = which ? ctx : x;
    const int hh = tokc / W_DIM, ww = tokc - hh * W_DIM;
    const float QSCALE = 0.0625f * 1.4426950408889634f;

    // y frags: lane = token l31, channels blk*16 + chb + 0..7
    short8_t yfr[16];
    #pragma unroll
    for (int blk = 0; blk < 16; ++blk) {
        float yv[8];
        #pragma unroll
        for (int j = 0; j < 8; ++j) {
            int ch = blk * 16 + chb + j;
            float pos = (ch < 128) ? col_embed[ww * 128 + ch]
                                   : row_embed[hh * 128 + (ch - 128)];
            yv[j] = img[ch * N_TOK + tokc] + pos;
        }
        union { unsigned u[4]; short8_t v; } pk;
        #pragma unroll
        for (int j = 0; j < 4; ++j) pk.u[j] = pack2bf(yv[2 * j], yv[2 * j + 1]);
        yfr[blk] = pk.v;
    }

    // GEMM1: tok^T = W_in . y^T  (+ b_in) -> bf16 B-frags in registers
    short8_t tokfr[16];
    #pragma unroll
    for (int ct = 0; ct < 8; ++ct) {
        f32x16 c;
        #pragma unroll
        for (int r = 0; r < 16; ++r) c[r] = 0.f;
        #pragma unroll
        for (int blk = 0; blk < 16; ++blk) {
            short8_t wf = *(const short8_t*)(Wb + (size_t)(ct * 32 + l31) * 256 + blk * 16 + chb);
            c = __builtin_amdgcn_mfma_f32_32x32x16_bf16(wf, yfr[blk], c, 0, 0, 0);
        }
        #pragma unroll
        for (int m = 0; m < 4; ++m) {
            float4 b4 = *(const float4*)(b_in + ct * 32 + 4 * h + 8 * m);
            c[4 * m + 0] += b4.x; c[4 * m + 1] += b4.y;
            c[4 * m + 2] += b4.z; c[4 * m + 3] += b4.w;
        }
        tokfr[2 * ct]     = mkfrag(c, 0);
        tokfr[2 * ct + 1] = mkfrag(c, 1);
    }

    // GEMM2
    if (which == 0) {
        gemm2_rowmajor(tokfr, Wb + 65536, bq, QSCALE, Qb, tok, l31, h);
    } else {
        gemm2_rowmajor(tokfr, Wb + 2 * 65536, bk, 1.f, Kb, tok, l31, h);
        gemm2_vt(tokfr, Wb + 3 * 65536, bv, Vt, tok, l31, h);
    }
}

// ---------------------------------------------------------------------------
// Kernel 4: MFMA flash attention, no-max softmax. Block = 8 waves = 1 qtile x
// 8 ksplits of 20 tiles each (k-space padded to 160 tiles; pads fully masked).
// Wave: 32 queries x 1 head. Swapped QK^T (S^T), O^T = V^T . P^T.
// Output packed bf16 to AOb [tok][256].
// ---------------------------------------------------------------------------
__global__ __launch_bounds__(512) void attn_mfma_kernel(
    const unsigned short* __restrict__ Qb, const unsigned short* __restrict__ Kb,
    const unsigned short* __restrict__ Vt, const unsigned* __restrict__ pmT,
    unsigned short* __restrict__ AOb)
{
    __shared__ float comb[7][17][64];

    const int t    = threadIdx.x;
    const int lane = t & 63;
    const int ks   = t >> 6;
    const int bid  = blockIdx.x;
    const int head = bid & 7;
    const int q0   = (bid >> 3) * 32;
    const int l31  = lane & 31;
    const int h    = lane >> 5;
    const int grp8 = h * 8;

    const unsigned short* Kh = Kb + (size_t)head * TPAD * 32;
    const unsigned short* Qh = Qb + (size_t)head * TPAD * 32;
    const unsigned short* Vh = Vt + ((size_t)head * 32 + l31) * VTP;

    short8_t qf0 = *(const short8_t*)(Qh + (size_t)(q0 + l31) * 32 + grp8);
    short8_t qf1 = *(const short8_t*)(Qh + (size_t)(q0 + l31) * 32 + 16 + grp8);

    f32x16 oacc;
    #pragma unroll
    for (int r = 0; r < 16; ++r) oacc[r] = 0.f;
    float lsum = 0.f;

    const int kt0 = ks * 20;

    short8_t ka0, ka1, va0, va1; unsigned mw;
    {   // preload first tile
        int k0 = kt0 * 32;
        const unsigned short* kp = Kh + (size_t)(k0 + l31) * 32 + grp8;
        ka0 = *(const short8_t*)kp;
        ka1 = *(const short8_t*)(kp + 16);
        va0 = *(const short8_t*)(Vh + k0 + grp8);
        va1 = *(const short8_t*)(Vh + k0 + 16 + grp8);
        mw  = pmT[(size_t)kt0 * QPAD + q0 + l31];
    }

    #pragma unroll 2
    for (int it = 0; it < 20; ++it) {
        int itn = (it < 19) ? it + 1 : it;
        int k0n = (kt0 + itn) * 32;
        const unsigned short* kpn = Kh + (size_t)(k0n + l31) * 32 + grp8;
        short8_t nka0 = *(const short8_t*)kpn;
        short8_t nka1 = *(const short8_t*)(kpn + 16);
        short8_t nva0 = *(const short8_t*)(Vh + k0n + grp8);
        short8_t nva1 = *(const short8_t*)(Vh + k0n + 16 + grp8);
        unsigned nmw  = pmT[(size_t)(kt0 + itn) * QPAD + q0 + l31];

        // S^T = K . Q^T (rows: keys, cols: queries); Q carries scale*log2e
        f32x16 sacc;
        #pragma unroll
        for (int r = 0; r < 16; ++r) sacc[r] = 0.f;
        sacc = __builtin_amdgcn_mfma_f32_32x32x16_bf16(ka0, qf0, sacc, 0, 0, 0);
        sacc = __builtin_amdgcn_mfma_f32_32x32x16_bf16(ka1, qf1, sacc, 0, 0, 0);

        unsigned wga[4];
        wga[0] = mw >> (4 * h);      wga[1] = mw >> (8 + 4 * h);
        wga[2] = mw >> (16 + 4 * h); wga[3] = mw >> (24 + 4 * h);

        float p[16];
        #pragma unroll
        for (int r = 0; r < 16; ++r) {
            float e = __builtin_amdgcn_exp2f(sacc[r]);
            p[r] = ((wga[r >> 2] >> (r & 3)) & 1u) ? 0.f : e;
        }
        {
            float s0 = (p[0] + p[1]) + (p[2] + p[3]);
            float s1 = (p[4] + p[5]) + (p[6] + p[7]);
            float s2 = (p[8] + p[9]) + (p[10] + p[11]);
            float s3 = (p[12] + p[13]) + (p[14] + p[15]);
            lsum += (s0 + s1) + (s2 + s3);
        }

        #pragma unroll
        for (int c = 0; c < 2; ++c) {
            const int b = 8 * c;
            unsigned a0 = pack2bf(p[b + 0], p[b + 1]);
            unsigned b0 = pack2bf(p[b + 4], p[b + 5]);
            unsigned a1 = pack2bf(p[b + 2], p[b + 3]);
            unsigned b1 = pack2bf(p[b + 6], p[b + 7]);
            uint2v s02 = __builtin_amdgcn_permlane32_swap(a0, b0, false, false);
            uint2v s13 = __builtin_amdgcn_permlane32_swap(a1, b1, false, false);
            union { unsigned u[4]; short8_t v; } fr;
            fr.u[0] = s02.x; fr.u[1] = s13.x; fr.u[2] = s02.y; fr.u[3] = s13.y;
            oacc = __builtin_amdgcn_mfma_f32_32x32x16_bf16(c ? va1 : va0, fr.v, oacc, 0, 0, 0);
        }

        ka0 = nka0; ka1 = nka1; va0 = nva0; va1 = nva1; mw = nmw;
    }

    float lfull = lsum + __shfl_xor(lsum, 32);

    if (ks) {
        comb[ks - 1][0][lane] = lfull;
        #pragma unroll
        for (int r = 0; r < 16; ++r) comb[ks - 1][1 + r][lane] = oacc[r];
    }
    __syncthreads();
    if (ks == 0) {
        float den = lfull;
        #pragma unroll
        for (int s = 0; s < 7; ++s) den += comb[s][0][lane];
        float inv = 1.f / den;
        f32x16 oc2;
        #pragma unroll
        for (int r = 0; r < 16; ++r) {
            float o = oacc[r];
            #pragma unroll
            for (int s = 0; s < 7; ++s) o += comb[s][1 + r][lane];
            oc2[r] = o * inv;
        }
        short8_t f0 = mkfrag(oc2, 0), f1 = mkfrag(oc2, 1);
        int q = q0 + l31;
        if (q < N_TOK) {
            *(short8_t*)(AOb + (size_t)q * EMB_D + head * 32 + grp8)      = f0;
            *(short8_t*)(AOb + (size_t)q * EMB_D + head * 32 + 16 + grp8) = f1;
        }
    }
}

// ---------------------------------------------------------------------------
// Kernel 5: MFMA output projection. out[c][n] = w_out[c].AO[n] + b_out[c].
// 1 wave / 32-token tile, grid 157. C-layout == channel-major output.
// ---------------------------------------------------------------------------
__global__ __launch_bounds__(64) void proj_out_kernel(
    const unsigned short* __restrict__ AOb, const unsigned short* __restrict__ Wob,
    const float* __restrict__ b_out, float* __restrict__ out)
{
    const int lane = threadIdx.x;
    const int l31 = lane & 31, h = lane >> 5;
    const int chb = 8 * h;
    const int tok0 = blockIdx.x * 32;
    const int tok  = tok0 + l31;
    const bool vld = tok < N_TOK;

    short8_t afr[16];
    #pragma unroll
    for (int blk = 0; blk < 16; ++blk)
        afr[blk] = *(const short8_t*)(AOb + (size_t)tok * EMB_D + blk * 16 + chb);

    #pragma unroll
    for (int ot = 0; ot < 8; ++ot) {
        f32x16 c;
        #pragma unroll
        for (int r = 0; r < 16; ++r) c[r] = 0.f;
        #pragma unroll
        for (int blk = 0; blk < 16; ++blk) {
            short8_t wf = *(const short8_t*)(Wob + (size_t)(ot * 32 + l31) * 256 + blk * 16 + chb);
            c = __builtin_amdgcn_mfma_f32_32x32x16_bf16(wf, afr[blk], c, 0, 0, 0);
        }
        #pragma unroll
        for (int m = 0; m < 4; ++m) {
            float4 b4 = *(const float4*)(b_out + ot * 32 + 4 * h + 8 * m);
            if (vld) {
                int row = ot * 32 + 4 * h + 8 * m;
                out[(size_t)(row + 0) * N_TOK + tok] = c[4 * m + 0] + b4.x;
                out[(size_t)(row + 1) * N_TOK + tok] = c[4 * m + 1] + b4.y;
                out[(size_t)(row + 2) * N_TOK + tok] = c[4 * m + 2] + b4.z;
                out[(size_t)(row + 3) * N_TOK + tok] = c[4 * m + 3] + b4.w;
            }
        }
    }
}

// ---------------------------------------------------------------------------
extern "C" void kernel_launch(void* const* d_in, const int* in_sizes, int n_in,
                              void* d_out, int out_size, void* d_ws, size_t ws_size,
                              hipStream_t stream) {
    const float* x         = (const float*)d_in[0];
    const float* ctx       = (const float*)d_in[1];
    const void*  mask      = (const void*) d_in[2];
    const float* row_embed = (const float*)d_in[3];
    const float* col_embed = (const float*)d_in[4];
    const float* w_in      = (const float*)d_in[5];
    const float* b_in      = (const float*)d_in[6];
    const float* wq        = (const float*)d_in[7];
    const float* bq        = (const float*)d_in[8];
    const float* wk        = (const float*)d_in[9];
    const float* bk        = (const float*)d_in[10];
    const float* wv        = (const float*)d_in[11];
    const float* bv        = (const float*)d_in[12];
    const float* w_out     = (const float*)d_in[13];
    const float* b_out     = (const float*)d_in[14];
    float* out = (float*)d_out;

    char* ws = (char*)d_ws;
    unsigned short* Qb  = (unsigned short*)(ws);                    // 2,621,440 B
    unsigned short* Kb  = (unsigned short*)(ws + 2621440);          // 2,621,440 B
    unsigned short* Vt  = (unsigned short*)(ws + 5242880);          // 2,621,440 B
    unsigned*       pmT = (unsigned*)      (ws + 7864320);          // 3,235,840 B
    unsigned short* AOb = (unsigned short*)(ws + 11100160);         // 2,621,440 B
    unsigned short* Wb  = (unsigned short*)(ws + 13721600);         //   655,360 B
    int*       maskflag = (int*)           (ws + 14376960);

    detect_mask_kernel<<<1, 64, 0, stream>>>((const unsigned*)mask, maskflag);
    pack_mask_kernel<<<dim3(20, NKT_PAD), 256, 0, stream>>>(mask, maskflag, pmT);
    wb16_kernel<<<dim3(64, 5), 256, 0, stream>>>(w_in, wq, wk, wv, w_out, Wb);
    embed_qkv_kernel<<<dim3(NKT, 2), 64, 0, stream>>>(
        x, ctx, row_embed, col_embed, Wb, b_in, bq, bk, bv, Qb, Kb, Vt);
    attn_mfma_kernel<<<dim3(NKT * 8), 512, 0, stream>>>(Qb, Kb, Vt, pmT, AOb);
    proj_out_kernel<<<dim3(NKT), 64, 0, stream>>>(AOb, Wb + 4 * 65536, b_out, out);
}

// Round 7
// 169.409 us; speedup vs baseline: 13.6167x; 1.2685x over previous
//
#include <hip/hip_runtime.h>
#include <hip/hip_bf16.h>
#include <math.h>

#define N_TOK 5000
#define EMB_D 256
#define W_DIM 100
#define TPAD 5120
#define VTP  5120
#define QPAD 5056
#define NKT  157
#define NKT_PAD 160

typedef __attribute__((ext_vector_type(8)))  short short8_t;
typedef __attribute__((ext_vector_type(16))) float f32x16;
typedef __attribute__((ext_vector_type(2)))  unsigned uint2v;

__device__ __forceinline__ unsigned f2bf(float x) {
    union { float f; unsigned u; } c; c.f = x;
    return (c.u + 0x8000u) >> 16;
}
__device__ __forceinline__ unsigned pack2bf(float lo, float hi) {
    __hip_bfloat162 h2 = __float22bfloat162_rn(make_float2(lo, hi));
    union { __hip_bfloat162 h; unsigned u; } c; c.h = h2;
    return c.u;
}
// C rows (crow(r,h) mapping) -> bf16 operand frag for 16-row block cb:
// lane holds rows cb*16 + 8h..8h+7 (contiguous bf16), col = l31.
__device__ __forceinline__ short8_t mkfrag(const f32x16& c, int cb) {
    const int b = 8 * cb;
    unsigned a0 = pack2bf(c[b + 0], c[b + 1]);
    unsigned a1 = pack2bf(c[b + 2], c[b + 3]);
    unsigned b0 = pack2bf(c[b + 4], c[b + 5]);
    unsigned b1 = pack2bf(c[b + 6], c[b + 7]);
    uint2v s02 = __builtin_amdgcn_permlane32_swap(a0, b0, false, false);
    uint2v s13 = __builtin_amdgcn_permlane32_swap(a1, b1, false, false);
    union { unsigned u[4]; short8_t v; } fr;
    fr.u[0] = s02.x; fr.u[1] = s13.x; fr.u[2] = s02.y; fr.u[3] = s13.y;
    return fr.v;
}

// ---------------------------------------------------------------------------
// Kernel 0: detect mask dtype (word 0/1/1.0f vs packed bytes). 1 wave.
// ---------------------------------------------------------------------------
__global__ void detect_mask_kernel(const unsigned* __restrict__ mask,
                                   int* __restrict__ flag) {
    int t = threadIdx.x;
    bool bad = false;
    for (int i = 0; i < 16; ++i) {
        unsigned w = mask[t * 16 + i];
        if (w != 0u && w != 1u && w != 0x3F800000u) bad = true;
    }
    unsigned long long bb = __ballot(bad);
    if (t == 0) *flag = (bb != 0ull) ? 1 : 0;
}

// ---------------------------------------------------------------------------
// Kernel 1: pack mask to bits, transposed: pmT[kt][q] bit j = masked(q, kt*32+j)
// kt in [157,160) -> all-masked (padding tiles).
// ---------------------------------------------------------------------------
__global__ __launch_bounds__(256) void pack_mask_kernel(
    const void* __restrict__ mask_raw, const int* __restrict__ flag,
    unsigned* __restrict__ pmT)
{
    int q  = blockIdx.x * 256 + threadIdx.x;
    int kt = blockIdx.y;
    if (q >= N_TOK) return;
    int k0 = kt * 32;
    if (k0 >= N_TOK) {
        pmT[(size_t)kt * QPAD + q] = 0xFFFFFFFFu;
        return;
    }
    unsigned bits = 0;
    if (*flag) {  // byte mask
        const unsigned* src = (const unsigned*)((const char*)mask_raw + ((size_t)q * N_TOK + k0));
        #pragma unroll
        for (int w = 0; w < 8; ++w) {
            unsigned u = src[w];
            #pragma unroll
            for (int b = 0; b < 4; ++b)
                if (u & (0xFFu << (8 * b))) bits |= 1u << (4 * w + b);
        }
    } else {      // int32 mask
        const int4* src = (const int4*)((const int*)mask_raw + (size_t)q * N_TOK + k0);
        #pragma unroll
        for (int w = 0; w < 8; ++w) {
            int4 u = src[w];
            if (u.x) bits |= 1u << (4 * w + 0);
            if (u.y) bits |= 1u << (4 * w + 1);
            if (u.z) bits |= 1u << (4 * w + 2);
            if (u.w) bits |= 1u << (4 * w + 3);
        }
    }
    if (k0 + 32 > N_TOK) {
        #pragma unroll
        for (int j = 0; j < 32; ++j)
            if (k0 + j >= N_TOK) bits |= 1u << j;
    }
    pmT[(size_t)kt * QPAD + q] = bits;
}

// ---------------------------------------------------------------------------
// Kernel 2: convert the 5 weight matrices (256x256 f32) to bf16. grid (64,5).
// Wb layout: [w_in | wq | wk | wv | w_out], each 65536 bf16.
// ---------------------------------------------------------------------------
__global__ __launch_bounds__(256) void wb16_kernel(
    const float* __restrict__ w_in, const float* __restrict__ wq,
    const float* __restrict__ wk, const float* __restrict__ wv,
    const float* __restrict__ w_out, unsigned short* __restrict__ Wb)
{
    const float* srcs[5] = {w_in, wq, wk, wv, w_out};
    const float* s = srcs[blockIdx.y];
    unsigned short* d = Wb + (size_t)blockIdx.y * 65536;
    int i = (blockIdx.x * 256 + threadIdx.x) * 4;
    float4 v = *(const float4*)(s + i);
    uint2 u;
    u.x = pack2bf(v.x, v.y);
    u.y = pack2bf(v.z, v.w);
    *(uint2*)&d[i] = u;
}

// ---------------------------------------------------------------------------
// Kernel 3: MFMA fused embed. grid (157, 3), block 256 (4 waves).
// y=0: Q from x. y=1: K from ctx. y=2: V^T from ctx.
// GEMM1 split across waves by output-channel pair (ct = 2w, 2w+1), tokfr
// frags shared via LDS; GEMM2: each wave owns ot in {2w, 2w+1}.
// ---------------------------------------------------------------------------
__global__ __launch_bounds__(256) void embed_qkv_kernel(
    const float* __restrict__ x, const float* __restrict__ ctx,
    const float* __restrict__ row_embed, const float* __restrict__ col_embed,
    const unsigned short* __restrict__ Wb,
    const float* __restrict__ b_in, const float* __restrict__ bq,
    const float* __restrict__ bk, const float* __restrict__ bv,
    unsigned short* __restrict__ Qb, unsigned short* __restrict__ Kb,
    unsigned short* __restrict__ Vt)
{
    __shared__ __align__(16) short8_t toksh[16][64];

    const int t = threadIdx.x;
    const int lane = t & 63;
    const int w = t >> 6;                    // wave 0..3
    const int l31 = lane & 31, h = lane >> 5;
    const int chb = 8 * h;
    const int which = blockIdx.y;            // 0:Q(x) 1:K(ctx) 2:V(ctx)
    const int tok0 = blockIdx.x * 32;
    const int tok  = tok0 + l31;             // <= 5023 < TPAD
    const int tokc = min(tok, N_TOK - 1);    // clamp loads
    const float* img = (which == 0) ? x : ctx;
    const int hh = tokc / W_DIM, ww = tokc - hh * W_DIM;
    const float QSCALE = 0.0625f * 1.4426950408889634f;

    // y frags (all 16, redundantly per wave; lane-identical across waves)
    short8_t yfr[16];
    #pragma unroll
    for (int blk = 0; blk < 16; ++blk) {
        float yv[8];
        #pragma unroll
        for (int j = 0; j < 8; ++j) {
            int ch = blk * 16 + chb + j;
            float pos = (ch < 128) ? col_embed[ww * 128 + ch]
                                   : row_embed[hh * 128 + (ch - 128)];
            yv[j] = img[ch * N_TOK + tokc] + pos;
        }
        union { unsigned u[4]; short8_t v; } pk;
        #pragma unroll
        for (int j = 0; j < 4; ++j) pk.u[j] = pack2bf(yv[2 * j], yv[2 * j + 1]);
        yfr[blk] = pk.v;
    }

    // GEMM1: wave w computes output channels ct = 2w, 2w+1 (32 MFMA)
    #pragma unroll
    for (int i = 0; i < 2; ++i) {
        const int ct = 2 * w + i;
        f32x16 c;
        #pragma unroll
        for (int r = 0; r < 16; ++r) c[r] = 0.f;
        #pragma unroll
        for (int blk = 0; blk < 16; ++blk) {
            short8_t wf = *(const short8_t*)(Wb + (size_t)(ct * 32 + l31) * 256 + blk * 16 + chb);
            c = __builtin_amdgcn_mfma_f32_32x32x16_bf16(wf, yfr[blk], c, 0, 0, 0);
        }
        #pragma unroll
        for (int m = 0; m < 4; ++m) {
            float4 b4 = *(const float4*)(b_in + ct * 32 + 4 * h + 8 * m);
            c[4 * m + 0] += b4.x; c[4 * m + 1] += b4.y;
            c[4 * m + 2] += b4.z; c[4 * m + 3] += b4.w;
        }
        toksh[4 * w + 2 * i + 0][lane] = mkfrag(c, 0);
        toksh[4 * w + 2 * i + 1][lane] = mkfrag(c, 1);
    }
    __syncthreads();
    short8_t tokfr[16];
    #pragma unroll
    for (int blk = 0; blk < 16; ++blk) tokfr[blk] = toksh[blk][lane];

    // GEMM2: wave w owns ot = 2w, 2w+1
    const unsigned short* W2 = Wb + (which + 1) * 65536;   // wq / wk / wv
    const float* bias2 = (which == 0) ? bq : (which == 1) ? bk : bv;
    #pragma unroll
    for (int i = 0; i < 2; ++i) {
        const int ot = 2 * w + i;
        f32x16 c;
        #pragma unroll
        for (int r = 0; r < 16; ++r) c[r] = 0.f;
        #pragma unroll
        for (int blk = 0; blk < 16; ++blk) {
            short8_t wf = *(const short8_t*)(W2 + (size_t)(ot * 32 + l31) * 256 + blk * 16 + chb);
            c = __builtin_amdgcn_mfma_f32_32x32x16_bf16(wf, tokfr[blk], c, 0, 0, 0);
        }
        if (which == 0) {
            #pragma unroll
            for (int m = 0; m < 4; ++m) {
                float4 b4 = *(const float4*)(bias2 + ot * 32 + 4 * h + 8 * m);
                c[4 * m + 0] = (c[4 * m + 0] + b4.x) * QSCALE;
                c[4 * m + 1] = (c[4 * m + 1] + b4.y) * QSCALE;
                c[4 * m + 2] = (c[4 * m + 2] + b4.z) * QSCALE;
                c[4 * m + 3] = (c[4 * m + 3] + b4.w) * QSCALE;
            }
        } else {
            #pragma unroll
            for (int m = 0; m < 4; ++m) {
                float4 b4 = *(const float4*)(bias2 + ot * 32 + 4 * h + 8 * m);
                c[4 * m + 0] += b4.x; c[4 * m + 1] += b4.y;
                c[4 * m + 2] += b4.z; c[4 * m + 3] += b4.w;
            }
        }
        if (which == 2) {
            // V: transposed store [head*32+d][tok]
            #pragma unroll
            for (int r = 0; r < 16; ++r) {
                int vd = (r & 3) + 8 * (r >> 2) + 4 * h;
                Vt[(size_t)(ot * 32 + vd) * VTP + tok] = (unsigned short)f2bf(c[r]);
            }
        } else {
            unsigned short* dst = (which == 0) ? Qb : Kb;
            short8_t f0 = mkfrag(c, 0), f1 = mkfrag(c, 1);
            *(short8_t*)(dst + (size_t)ot * TPAD * 32 + (size_t)tok * 32 + chb)      = f0;
            *(short8_t*)(dst + (size_t)ot * TPAD * 32 + (size_t)tok * 32 + 16 + chb) = f1;
        }
    }
}

// ---------------------------------------------------------------------------
// Kernel 4: MFMA flash attention, no-max softmax. Block = 4 waves = 1 qtile x
// 4 ksplits of 40 tiles each (k-space padded to 160 tiles; pads fully masked).
// All 1256 blocks co-resident (13KB LDS, 64 VGPR) -> no dispatch tail.
// Wave: 32 queries x 1 head. Swapped QK^T (S^T), O^T = V^T . P^T.
// ---------------------------------------------------------------------------
__global__ __launch_bounds__(256) void attn_mfma_kernel(
    const unsigned short* __restrict__ Qb, const unsigned short* __restrict__ Kb,
    const unsigned short* __restrict__ Vt, const unsigned* __restrict__ pmT,
    unsigned short* __restrict__ AOb)
{
    __shared__ float comb[3][17][64];

    const int t    = threadIdx.x;
    const int lane = t & 63;
    const int ks   = t >> 6;                 // 0..3
    const int bid  = blockIdx.x;
    const int head = bid & 7;
    const int q0   = (bid >> 3) * 32;
    const int l31  = lane & 31;
    const int h    = lane >> 5;
    const int grp8 = h * 8;

    const unsigned short* Kh = Kb + (size_t)head * TPAD * 32;
    const unsigned short* Qh = Qb + (size_t)head * TPAD * 32;
    const unsigned short* Vh = Vt + ((size_t)head * 32 + l31) * VTP;

    short8_t qf0 = *(const short8_t*)(Qh + (size_t)(q0 + l31) * 32 + grp8);
    short8_t qf1 = *(const short8_t*)(Qh + (size_t)(q0 + l31) * 32 + 16 + grp8);

    f32x16 oacc;
    #pragma unroll
    for (int r = 0; r < 16; ++r) oacc[r] = 0.f;
    float lsum = 0.f;

    const int kt0 = ks * 40;

    short8_t ka0, ka1, va0, va1; unsigned mw;
    {   // preload first tile
        int k0 = kt0 * 32;
        const unsigned short* kp = Kh + (size_t)(k0 + l31) * 32 + grp8;
        ka0 = *(const short8_t*)kp;
        ka1 = *(const short8_t*)(kp + 16);
        va0 = *(const short8_t*)(Vh + k0 + grp8);
        va1 = *(const short8_t*)(Vh + k0 + 16 + grp8);
        mw  = pmT[(size_t)kt0 * QPAD + q0 + l31];
    }

    #pragma unroll 2
    for (int it = 0; it < 40; ++it) {
        int itn = (it < 39) ? it + 1 : it;
        int k0n = (kt0 + itn) * 32;
        const unsigned short* kpn = Kh + (size_t)(k0n + l31) * 32 + grp8;
        short8_t nka0 = *(const short8_t*)kpn;
        short8_t nka1 = *(const short8_t*)(kpn + 16);
        short8_t nva0 = *(const short8_t*)(Vh + k0n + grp8);
        short8_t nva1 = *(const short8_t*)(Vh + k0n + 16 + grp8);
        unsigned nmw  = pmT[(size_t)(kt0 + itn) * QPAD + q0 + l31];

        // S^T = K . Q^T (rows: keys, cols: queries); Q carries scale*log2e
        f32x16 sacc;
        #pragma unroll
        for (int r = 0; r < 16; ++r) sacc[r] = 0.f;
        sacc = __builtin_amdgcn_mfma_f32_32x32x16_bf16(ka0, qf0, sacc, 0, 0, 0);
        sacc = __builtin_amdgcn_mfma_f32_32x32x16_bf16(ka1, qf1, sacc, 0, 0, 0);

        unsigned wga[4];
        wga[0] = mw >> (4 * h);      wga[1] = mw >> (8 + 4 * h);
        wga[2] = mw >> (16 + 4 * h); wga[3] = mw >> (24 + 4 * h);

        float p[16];
        #pragma unroll
        for (int r = 0; r < 16; ++r) {
            float e = __builtin_amdgcn_exp2f(sacc[r]);
            p[r] = ((wga[r >> 2] >> (r & 3)) & 1u) ? 0.f : e;
        }
        {
            float s0 = (p[0] + p[1]) + (p[2] + p[3]);
            float s1 = (p[4] + p[5]) + (p[6] + p[7]);
            float s2 = (p[8] + p[9]) + (p[10] + p[11]);
            float s3 = (p[12] + p[13]) + (p[14] + p[15]);
            lsum += (s0 + s1) + (s2 + s3);
        }

        #pragma unroll
        for (int c = 0; c < 2; ++c) {
            const int b = 8 * c;
            unsigned a0 = pack2bf(p[b + 0], p[b + 1]);
            unsigned b0 = pack2bf(p[b + 4], p[b + 5]);
            unsigned a1 = pack2bf(p[b + 2], p[b + 3]);
            unsigned b1 = pack2bf(p[b + 6], p[b + 7]);
            uint2v s02 = __builtin_amdgcn_permlane32_swap(a0, b0, false, false);
            uint2v s13 = __builtin_amdgcn_permlane32_swap(a1, b1, false, false);
            union { unsigned u[4]; short8_t v; } fr;
            fr.u[0] = s02.x; fr.u[1] = s13.x; fr.u[2] = s02.y; fr.u[3] = s13.y;
            oacc = __builtin_amdgcn_mfma_f32_32x32x16_bf16(c ? va1 : va0, fr.v, oacc, 0, 0, 0);
        }

        ka0 = nka0; ka1 = nka1; va0 = nva0; va1 = nva1; mw = nmw;
    }

    float lfull = lsum + __shfl_xor(lsum, 32);

    if (ks) {
        comb[ks - 1][0][lane] = lfull;
        #pragma unroll
        for (int r = 0; r < 16; ++r) comb[ks - 1][1 + r][lane] = oacc[r];
    }
    __syncthreads();
    if (ks == 0) {
        float den = lfull;
        #pragma unroll
        for (int s = 0; s < 3; ++s) den += comb[s][0][lane];
        float inv = 1.f / den;
        f32x16 oc2;
        #pragma unroll
        for (int r = 0; r < 16; ++r) {
            float o = oacc[r];
            #pragma unroll
            for (int s = 0; s < 3; ++s) o += comb[s][1 + r][lane];
            oc2[r] = o * inv;
        }
        short8_t f0 = mkfrag(oc2, 0), f1 = mkfrag(oc2, 1);
        int q = q0 + l31;
        if (q < N_TOK) {
            *(short8_t*)(AOb + (size_t)q * EMB_D + head * 32 + grp8)      = f0;
            *(short8_t*)(AOb + (size_t)q * EMB_D + head * 32 + 16 + grp8) = f1;
        }
    }
}

// ---------------------------------------------------------------------------
// Kernel 5: MFMA output projection. grid (157, 8): blockIdx.y = ot (32 output
// channels). 1 wave/block, 16 MFMA. C-layout == channel-major output.
// ---------------------------------------------------------------------------
__global__ __launch_bounds__(64) void proj_out_kernel(
    const unsigned short* __restrict__ AOb, const unsigned short* __restrict__ Wob,
    const float* __restrict__ b_out, float* __restrict__ out)
{
    const int lane = threadIdx.x;
    const int l31 = lane & 31, h = lane >> 5;
    const int chb = 8 * h;
    const int tok0 = blockIdx.x * 32;
    const int tok  = tok0 + l31;
    const bool vld = tok < N_TOK;
    const int ot = blockIdx.y;

    short8_t afr[16];
    #pragma unroll
    for (int blk = 0; blk < 16; ++blk)
        afr[blk] = *(const short8_t*)(AOb + (size_t)tok * EMB_D + blk * 16 + chb);

    f32x16 c;
    #pragma unroll
    for (int r = 0; r < 16; ++r) c[r] = 0.f;
    #pragma unroll
    for (int blk = 0; blk < 16; ++blk) {
        short8_t wf = *(const short8_t*)(Wob + (size_t)(ot * 32 + l31) * 256 + blk * 16 + chb);
        c = __builtin_amdgcn_mfma_f32_32x32x16_bf16(wf, afr[blk], c, 0, 0, 0);
    }
    #pragma unroll
    for (int m = 0; m < 4; ++m) {
        float4 b4 = *(const float4*)(b_out + ot * 32 + 4 * h + 8 * m);
        if (vld) {
            int row = ot * 32 + 4 * h + 8 * m;
            out[(size_t)(row + 0) * N_TOK + tok] = c[4 * m + 0] + b4.x;
            out[(size_t)(row + 1) * N_TOK + tok] = c[4 * m + 1] + b4.y;
            out[(size_t)(row + 2) * N_TOK + tok] = c[4 * m + 2] + b4.z;
            out[(size_t)(row + 3) * N_TOK + tok] = c[4 * m + 3] + b4.w;
        }
    }
}

// ---------------------------------------------------------------------------
extern "C" void kernel_launch(void* const* d_in, const int* in_sizes, int n_in,
                              void* d_out, int out_size, void* d_ws, size_t ws_size,
                              hipStream_t stream) {
    const float* x         = (const float*)d_in[0];
    const float* ctx       = (const float*)d_in[1];
    const void*  mask      = (const void*) d_in[2];
    const float* row_embed = (const float*)d_in[3];
    const float* col_embed = (const float*)d_in[4];
    const float* w_in      = (const float*)d_in[5];
    const float* b_in      = (const float*)d_in[6];
    const float* wq        = (const float*)d_in[7];
    const float* bq        = (const float*)d_in[8];
    const float* wk        = (const float*)d_in[9];
    const float* bk        = (const float*)d_in[10];
    const float* wv        = (const float*)d_in[11];
    const float* bv        = (const float*)d_in[12];
    const float* w_out     = (const float*)d_in[13];
    const float* b_out     = (const float*)d_in[14];
    float* out = (float*)d_out;

    char* ws = (char*)d_ws;
    unsigned short* Qb  = (unsigned short*)(ws);                    // 2,621,440 B
    unsigned short* Kb  = (unsigned short*)(ws + 2621440);          // 2,621,440 B
    unsigned short* Vt  = (unsigned short*)(ws + 5242880);          // 2,621,440 B
    unsigned*       pmT = (unsigned*)      (ws + 7864320);          // 3,235,840 B
    unsigned short* AOb = (unsigned short*)(ws + 11100160);         // 2,621,440 B
    unsigned short* Wb  = (unsigned short*)(ws + 13721600);         //   655,360 B
    int*       maskflag = (int*)           (ws + 14376960);

    detect_mask_kernel<<<1, 64, 0, stream>>>((const unsigned*)mask, maskflag);
    pack_mask_kernel<<<dim3(20, NKT_PAD), 256, 0, stream>>>(mask, maskflag, pmT);
    wb16_kernel<<<dim3(64, 5), 256, 0, stream>>>(w_in, wq, wk, wv, w_out, Wb);
    embed_qkv_kernel<<<dim3(NKT, 3), 256, 0, stream>>>(
        x, ctx, row_embed, col_embed, Wb, b_in, bq, bk, bv, Qb, Kb, Vt);
    attn_mfma_kernel<<<dim3(NKT * 8), 256, 0, stream>>>(Qb, Kb, Vt, pmT, AOb);
    proj_out_kernel<<<dim3(NKT, 8), 64, 0, stream>>>(AOb, Wb + 4 * 65536, b_out, out);
}

// Round 8
// 138.969 us; speedup vs baseline: 16.5992x; 1.2190x over previous
//
#include <hip/hip_runtime.h>
#include <hip/hip_bf16.h>
#include <math.h>

#define N_TOK 5000
#define EMB_D 256
#define W_DIM 100
#define TPAD 5120
#define QPAD 5056
#define NKT  157
#define NKT_PAD 160

typedef __attribute__((ext_vector_type(8)))  short short8_t;
typedef __attribute__((ext_vector_type(16))) float f32x16;
typedef __attribute__((ext_vector_type(2)))  unsigned uint2v;

__device__ __forceinline__ unsigned f2bf(float x) {
    union { float f; unsigned u; } c; c.f = x;
    return (c.u + 0x8000u) >> 16;
}
__device__ __forceinline__ unsigned pack2bf(float lo, float hi) {
    __hip_bfloat162 h2 = __float22bfloat162_rn(make_float2(lo, hi));
    union { __hip_bfloat162 h; unsigned u; } c; c.h = h2;
    return c.u;
}
// C rows (crow(r,h) mapping) -> bf16 operand frag for 16-row block cb:
// lane holds rows cb*16 + 8h..8h+7 (contiguous bf16), col = l31.
__device__ __forceinline__ short8_t mkfrag(const f32x16& c, int cb) {
    const int b = 8 * cb;
    unsigned a0 = pack2bf(c[b + 0], c[b + 1]);
    unsigned a1 = pack2bf(c[b + 2], c[b + 3]);
    unsigned b0 = pack2bf(c[b + 4], c[b + 5]);
    unsigned b1 = pack2bf(c[b + 6], c[b + 7]);
    uint2v s02 = __builtin_amdgcn_permlane32_swap(a0, b0, false, false);
    uint2v s13 = __builtin_amdgcn_permlane32_swap(a1, b1, false, false);
    union { unsigned u[4]; short8_t v; } fr;
    fr.u[0] = s02.x; fr.u[1] = s13.x; fr.u[2] = s02.y; fr.u[3] = s13.y;
    return fr.v;
}

// ---------------------------------------------------------------------------
// Kernel 0: detect mask dtype (word 0/1/1.0f vs packed bytes). 1 wave.
// ---------------------------------------------------------------------------
__global__ void detect_mask_kernel(const unsigned* __restrict__ mask,
                                   int* __restrict__ flag) {
    int t = threadIdx.x;
    bool bad = false;
    for (int i = 0; i < 16; ++i) {
        unsigned w = mask[t * 16 + i];
        if (w != 0u && w != 1u && w != 0x3F800000u) bad = true;
    }
    unsigned long long bb = __ballot(bad);
    if (t == 0) *flag = (bb != 0ull) ? 1 : 0;
}

// ---------------------------------------------------------------------------
// Kernel 1: pack mask to bits, transposed: pmT[kt][q] bit j = masked(q, kt*32+j)
// kt in [157,160) -> all-masked (padding tiles).
// ---------------------------------------------------------------------------
__global__ __launch_bounds__(256) void pack_mask_kernel(
    const void* __restrict__ mask_raw, const int* __restrict__ flag,
    unsigned* __restrict__ pmT)
{
    int q  = blockIdx.x * 256 + threadIdx.x;
    int kt = blockIdx.y;
    if (q >= N_TOK) return;
    int k0 = kt * 32;
    if (k0 >= N_TOK) {
        pmT[(size_t)kt * QPAD + q] = 0xFFFFFFFFu;
        return;
    }
    unsigned bits = 0;
    if (*flag) {  // byte mask
        const unsigned* src = (const unsigned*)((const char*)mask_raw + ((size_t)q * N_TOK + k0));
        #pragma unroll
        for (int w = 0; w < 8; ++w) {
            unsigned u = src[w];
            #pragma unroll
            for (int b = 0; b < 4; ++b)
                if (u & (0xFFu << (8 * b))) bits |= 1u << (4 * w + b);
        }
    } else {      // int32 mask
        const int4* src = (const int4*)((const int*)mask_raw + (size_t)q * N_TOK + k0);
        #pragma unroll
        for (int w = 0; w < 8; ++w) {
            int4 u = src[w];
            if (u.x) bits |= 1u << (4 * w + 0);
            if (u.y) bits |= 1u << (4 * w + 1);
            if (u.z) bits |= 1u << (4 * w + 2);
            if (u.w) bits |= 1u << (4 * w + 3);
        }
    }
    if (k0 + 32 > N_TOK) {
        #pragma unroll
        for (int j = 0; j < 32; ++j)
            if (k0 + j >= N_TOK) bits |= 1u << j;
    }
    pmT[(size_t)kt * QPAD + q] = bits;
}

// ---------------------------------------------------------------------------
// Kernel 2: convert the 5 weight matrices (256x256 f32) to bf16. grid (64,5).
// Wb layout: [w_in | wq | wk | wv | w_out], each 65536 bf16.
// ---------------------------------------------------------------------------
__global__ __launch_bounds__(256) void wb16_kernel(
    const float* __restrict__ w_in, const float* __restrict__ wq,
    const float* __restrict__ wk, const float* __restrict__ wv,
    const float* __restrict__ w_out, unsigned short* __restrict__ Wb)
{
    const float* srcs[5] = {w_in, wq, wk, wv, w_out};
    const float* s = srcs[blockIdx.y];
    unsigned short* d = Wb + (size_t)blockIdx.y * 65536;
    int i = (blockIdx.x * 256 + threadIdx.x) * 4;
    float4 v = *(const float4*)(s + i);
    uint2 u;
    u.x = pack2bf(v.x, v.y);
    u.y = pack2bf(v.z, v.w);
    *(uint2*)&d[i] = u;
}

// ---------------------------------------------------------------------------
// Kernel 3: MFMA fused embed. grid (157, 3), block 256 (4 waves).
// y=0: Q from x. y=1: K from ctx. y=2: V^T (k-tile-blocked) from ctx.
// GEMM1 split across waves by output-channel pair, tokfr shared via LDS.
// ---------------------------------------------------------------------------
__global__ __launch_bounds__(256) void embed_qkv_kernel(
    const float* __restrict__ x, const float* __restrict__ ctx,
    const float* __restrict__ row_embed, const float* __restrict__ col_embed,
    const unsigned short* __restrict__ Wb,
    const float* __restrict__ b_in, const float* __restrict__ bq,
    const float* __restrict__ bk, const float* __restrict__ bv,
    unsigned short* __restrict__ Qb, unsigned short* __restrict__ Kb,
    unsigned short* __restrict__ Vt)
{
    __shared__ __align__(16) short8_t toksh[16][64];

    const int t = threadIdx.x;
    const int lane = t & 63;
    const int w = t >> 6;                    // wave 0..3
    const int l31 = lane & 31, h = lane >> 5;
    const int chb = 8 * h;
    const int which = blockIdx.y;            // 0:Q(x) 1:K(ctx) 2:V(ctx)
    const int bx = blockIdx.x;
    const int tok0 = bx * 32;
    const int tok  = tok0 + l31;             // <= 5023 < TPAD
    const int tokc = min(tok, N_TOK - 1);    // clamp loads
    const float* img = (which == 0) ? x : ctx;
    const int hh = tokc / W_DIM, ww = tokc - hh * W_DIM;
    const float QSCALE = 0.0625f * 1.4426950408889634f;

    // y frags (all 16, redundantly per wave; lane-identical across waves)
    short8_t yfr[16];
    #pragma unroll
    for (int blk = 0; blk < 16; ++blk) {
        float yv[8];
        #pragma unroll
        for (int j = 0; j < 8; ++j) {
            int ch = blk * 16 + chb + j;
            float pos = (ch < 128) ? col_embed[ww * 128 + ch]
                                   : row_embed[hh * 128 + (ch - 128)];
            yv[j] = img[ch * N_TOK + tokc] + pos;
        }
        union { unsigned u[4]; short8_t v; } pk;
        #pragma unroll
        for (int j = 0; j < 4; ++j) pk.u[j] = pack2bf(yv[2 * j], yv[2 * j + 1]);
        yfr[blk] = pk.v;
    }

    // GEMM1: wave w computes output channels ct = 2w, 2w+1 (32 MFMA)
    #pragma unroll
    for (int i = 0; i < 2; ++i) {
        const int ct = 2 * w + i;
        f32x16 c;
        #pragma unroll
        for (int r = 0; r < 16; ++r) c[r] = 0.f;
        #pragma unroll
        for (int blk = 0; blk < 16; ++blk) {
            short8_t wf = *(const short8_t*)(Wb + (size_t)(ct * 32 + l31) * 256 + blk * 16 + chb);
            c = __builtin_amdgcn_mfma_f32_32x32x16_bf16(wf, yfr[blk], c, 0, 0, 0);
        }
        #pragma unroll
        for (int m = 0; m < 4; ++m) {
            float4 b4 = *(const float4*)(b_in + ct * 32 + 4 * h + 8 * m);
            c[4 * m + 0] += b4.x; c[4 * m + 1] += b4.y;
            c[4 * m + 2] += b4.z; c[4 * m + 3] += b4.w;
        }
        toksh[4 * w + 2 * i + 0][lane] = mkfrag(c, 0);
        toksh[4 * w + 2 * i + 1][lane] = mkfrag(c, 1);
    }
    __syncthreads();
    short8_t tokfr[16];
    #pragma unroll
    for (int blk = 0; blk < 16; ++blk) tokfr[blk] = toksh[blk][lane];

    // GEMM2: wave w owns ot = 2w, 2w+1
    const unsigned short* W2 = Wb + (which + 1) * 65536;   // wq / wk / wv
    const float* bias2 = (which == 0) ? bq : (which == 1) ? bk : bv;
    #pragma unroll
    for (int i = 0; i < 2; ++i) {
        const int ot = 2 * w + i;
        f32x16 c;
        #pragma unroll
        for (int r = 0; r < 16; ++r) c[r] = 0.f;
        #pragma unroll
        for (int blk = 0; blk < 16; ++blk) {
            short8_t wf = *(const short8_t*)(W2 + (size_t)(ot * 32 + l31) * 256 + blk * 16 + chb);
            c = __builtin_amdgcn_mfma_f32_32x32x16_bf16(wf, tokfr[blk], c, 0, 0, 0);
        }
        if (which == 0) {
            #pragma unroll
            for (int m = 0; m < 4; ++m) {
                float4 b4 = *(const float4*)(bias2 + ot * 32 + 4 * h + 8 * m);
                c[4 * m + 0] = (c[4 * m + 0] + b4.x) * QSCALE;
                c[4 * m + 1] = (c[4 * m + 1] + b4.y) * QSCALE;
                c[4 * m + 2] = (c[4 * m + 2] + b4.z) * QSCALE;
                c[4 * m + 3] = (c[4 * m + 3] + b4.w) * QSCALE;
            }
        } else {
            #pragma unroll
            for (int m = 0; m < 4; ++m) {
                float4 b4 = *(const float4*)(bias2 + ot * 32 + 4 * h + 8 * m);
                c[4 * m + 0] += b4.x; c[4 * m + 1] += b4.y;
                c[4 * m + 2] += b4.z; c[4 * m + 3] += b4.w;
            }
        }
        if (which == 2) {
            // V^T k-tile-blocked: [head][kt=bx][d][k=l31], tile = 1024 elems
            #pragma unroll
            for (int r = 0; r < 16; ++r) {
                int oc = ot * 32 + ((r & 3) + 8 * (r >> 2) + 4 * h);
                int hd = oc >> 5, d = oc & 31;
                Vt[(size_t)(hd * NKT_PAD + bx) * 1024 + d * 32 + l31] =
                    (unsigned short)f2bf(c[r]);
            }
        } else {
            unsigned short* dst = (which == 0) ? Qb : Kb;
            short8_t f0 = mkfrag(c, 0), f1 = mkfrag(c, 1);
            *(short8_t*)(dst + (size_t)ot * TPAD * 32 + (size_t)tok * 32 + chb)      = f0;
            *(short8_t*)(dst + (size_t)ot * TPAD * 32 + (size_t)tok * 32 + 16 + chb) = f1;
        }
    }
}

// ---------------------------------------------------------------------------
// Kernel 4: MFMA flash attention, no-max softmax. Block = 8 waves = 1 qtile x
// 8 ksplits of 20 tiles each (k-space padded to 160 tiles; pads fully masked).
// Wave: 32 queries x 1 head. Swapped QK^T (S^T), O^T = V^T . P^T.
// V^T is k-tile-blocked -> V loads are contiguous 2KB like K (coalesced).
// ---------------------------------------------------------------------------
__global__ __launch_bounds__(512) void attn_mfma_kernel(
    const unsigned short* __restrict__ Qb, const unsigned short* __restrict__ Kb,
    const unsigned short* __restrict__ Vt, const unsigned* __restrict__ pmT,
    unsigned short* __restrict__ AOb)
{
    __shared__ float comb[7][17][64];

    const int t    = threadIdx.x;
    const int lane = t & 63;
    const int ks   = t >> 6;                 // 0..7
    const int bid  = blockIdx.x;
    const int head = bid & 7;
    const int q0   = (bid >> 3) * 32;
    const int l31  = lane & 31;
    const int h    = lane >> 5;
    const int grp8 = h * 8;

    const unsigned short* Kh = Kb + (size_t)head * TPAD * 32;
    const unsigned short* Qh = Qb + (size_t)head * TPAD * 32;
    const unsigned short* Vh = Vt + (size_t)head * NKT_PAD * 1024 + l31 * 32 + grp8;

    short8_t qf0 = *(const short8_t*)(Qh + (size_t)(q0 + l31) * 32 + grp8);
    short8_t qf1 = *(const short8_t*)(Qh + (size_t)(q0 + l31) * 32 + 16 + grp8);

    f32x16 oacc;
    #pragma unroll
    for (int r = 0; r < 16; ++r) oacc[r] = 0.f;
    float lsum = 0.f;

    const int kt0 = ks * 20;

    short8_t ka0, ka1, va0, va1; unsigned mw;
    {   // preload first tile
        int k0 = kt0 * 32;
        const unsigned short* kp = Kh + (size_t)(k0 + l31) * 32 + grp8;
        ka0 = *(const short8_t*)kp;
        ka1 = *(const short8_t*)(kp + 16);
        va0 = *(const short8_t*)(Vh + kt0 * 1024);
        va1 = *(const short8_t*)(Vh + kt0 * 1024 + 16);
        mw  = pmT[(size_t)kt0 * QPAD + q0 + l31];
    }

    #pragma unroll 2
    for (int it = 0; it < 20; ++it) {
        int itn = (it < 19) ? it + 1 : it;
        int ktn = kt0 + itn;
        int k0n = ktn * 32;
        const unsigned short* kpn = Kh + (size_t)(k0n + l31) * 32 + grp8;
        short8_t nka0 = *(const short8_t*)kpn;
        short8_t nka1 = *(const short8_t*)(kpn + 16);
        const unsigned short* vpn = Vh + ktn * 1024;
        short8_t nva0 = *(const short8_t*)vpn;
        short8_t nva1 = *(const short8_t*)(vpn + 16);
        unsigned nmw  = pmT[(size_t)ktn * QPAD + q0 + l31];

        // S^T = K . Q^T (rows: keys, cols: queries); Q carries scale*log2e
        f32x16 sacc;
        #pragma unroll
        for (int r = 0; r < 16; ++r) sacc[r] = 0.f;
        sacc = __builtin_amdgcn_mfma_f32_32x32x16_bf16(ka0, qf0, sacc, 0, 0, 0);
        sacc = __builtin_amdgcn_mfma_f32_32x32x16_bf16(ka1, qf1, sacc, 0, 0, 0);

        unsigned wga[4];
        wga[0] = mw >> (4 * h);      wga[1] = mw >> (8 + 4 * h);
        wga[2] = mw >> (16 + 4 * h); wga[3] = mw >> (24 + 4 * h);

        float p[16];
        #pragma unroll
        for (int r = 0; r < 16; ++r) {
            float e = __builtin_amdgcn_exp2f(sacc[r]);
            p[r] = ((wga[r >> 2] >> (r & 3)) & 1u) ? 0.f : e;
        }
        {
            float s0 = (p[0] + p[1]) + (p[2] + p[3]);
            float s1 = (p[4] + p[5]) + (p[6] + p[7]);
            float s2 = (p[8] + p[9]) + (p[10] + p[11]);
            float s3 = (p[12] + p[13]) + (p[14] + p[15]);
            lsum += (s0 + s1) + (s2 + s3);
        }

        #pragma unroll
        for (int c = 0; c < 2; ++c) {
            const int b = 8 * c;
            unsigned a0 = pack2bf(p[b + 0], p[b + 1]);
            unsigned b0 = pack2bf(p[b + 4], p[b + 5]);
            unsigned a1 = pack2bf(p[b + 2], p[b + 3]);
            unsigned b1 = pack2bf(p[b + 6], p[b + 7]);
            uint2v s02 = __builtin_amdgcn_permlane32_swap(a0, b0, false, false);
            uint2v s13 = __builtin_amdgcn_permlane32_swap(a1, b1, false, false);
            union { unsigned u[4]; short8_t v; } fr;
            fr.u[0] = s02.x; fr.u[1] = s13.x; fr.u[2] = s02.y; fr.u[3] = s13.y;
            oacc = __builtin_amdgcn_mfma_f32_32x32x16_bf16(c ? va1 : va0, fr.v, oacc, 0, 0, 0);
        }

        ka0 = nka0; ka1 = nka1; va0 = nva0; va1 = nva1; mw = nmw;
    }

    float lfull = lsum + __shfl_xor(lsum, 32);

    if (ks) {
        comb[ks - 1][0][lane] = lfull;
        #pragma unroll
        for (int r = 0; r < 16; ++r) comb[ks - 1][1 + r][lane] = oacc[r];
    }
    __syncthreads();
    if (ks == 0) {
        float den = lfull;
        #pragma unroll
        for (int s = 0; s < 7; ++s) den += comb[s][0][lane];
        float inv = 1.f / den;
        f32x16 oc2;
        #pragma unroll
        for (int r = 0; r < 16; ++r) {
            float o = oacc[r];
            #pragma unroll
            for (int s = 0; s < 7; ++s) o += comb[s][1 + r][lane];
            oc2[r] = o * inv;
        }
        short8_t f0 = mkfrag(oc2, 0), f1 = mkfrag(oc2, 1);
        int q = q0 + l31;
        if (q < N_TOK) {
            *(short8_t*)(AOb + (size_t)q * EMB_D + head * 32 + grp8)      = f0;
            *(short8_t*)(AOb + (size_t)q * EMB_D + head * 32 + 16 + grp8) = f1;
        }
    }
}

// ---------------------------------------------------------------------------
// Kernel 5: MFMA output projection. grid (157, 8): blockIdx.y = ot (32 output
// channels). 1 wave/block, 16 MFMA. C-layout == channel-major output.
// ---------------------------------------------------------------------------
__global__ __launch_bounds__(64) void proj_out_kernel(
    const unsigned short* __restrict__ AOb, const unsigned short* __restrict__ Wob,
    const float* __restrict__ b_out, float* __restrict__ out)
{
    const int lane = threadIdx.x;
    const int l31 = lane & 31, h = lane >> 5;
    const int chb = 8 * h;
    const int tok0 = blockIdx.x * 32;
    const int tok  = tok0 + l31;
    const bool vld = tok < N_TOK;
    const int ot = blockIdx.y;

    short8_t afr[16];
    #pragma unroll
    for (int blk = 0; blk < 16; ++blk)
        afr[blk] = *(const short8_t*)(AOb + (size_t)tok * EMB_D + blk * 16 + chb);

    f32x16 c;
    #pragma unroll
    for (int r = 0; r < 16; ++r) c[r] = 0.f;
    #pragma unroll
    for (int blk = 0; blk < 16; ++blk) {
        short8_t wf = *(const short8_t*)(Wob + (size_t)(ot * 32 + l31) * 256 + blk * 16 + chb);
        c = __builtin_amdgcn_mfma_f32_32x32x16_bf16(wf, afr[blk], c, 0, 0, 0);
    }
    #pragma unroll
    for (int m = 0; m < 4; ++m) {
        float4 b4 = *(const float4*)(b_out + ot * 32 + 4 * h + 8 * m);
        if (vld) {
            int row = ot * 32 + 4 * h + 8 * m;
            out[(size_t)(row + 0) * N_TOK + tok] = c[4 * m + 0] + b4.x;
            out[(size_t)(row + 1) * N_TOK + tok] = c[4 * m + 1] + b4.y;
            out[(size_t)(row + 2) * N_TOK + tok] = c[4 * m + 2] + b4.z;
            out[(size_t)(row + 3) * N_TOK + tok] = c[4 * m + 3] + b4.w;
        }
    }
}

// ---------------------------------------------------------------------------
extern "C" void kernel_launch(void* const* d_in, const int* in_sizes, int n_in,
                              void* d_out, int out_size, void* d_ws, size_t ws_size,
                              hipStream_t stream) {
    const float* x         = (const float*)d_in[0];
    const float* ctx       = (const float*)d_in[1];
    const void*  mask      = (const void*) d_in[2];
    const float* row_embed = (const float*)d_in[3];
    const float* col_embed = (const float*)d_in[4];
    const float* w_in      = (const float*)d_in[5];
    const float* b_in      = (const float*)d_in[6];
    const float* wq        = (const float*)d_in[7];
    const float* bq        = (const float*)d_in[8];
    const float* wk        = (const float*)d_in[9];
    const float* bk        = (const float*)d_in[10];
    const float* wv        = (const float*)d_in[11];
    const float* bv        = (const float*)d_in[12];
    const float* w_out     = (const float*)d_in[13];
    const float* b_out     = (const float*)d_in[14];
    float* out = (float*)d_out;

    char* ws = (char*)d_ws;
    unsigned short* Qb  = (unsigned short*)(ws);                    // 2,621,440 B
    unsigned short* Kb  = (unsigned short*)(ws + 2621440);          // 2,621,440 B
    unsigned short* Vt  = (unsigned short*)(ws + 5242880);          // 2,621,440 B
    unsigned*       pmT = (unsigned*)      (ws + 7864320);          // 3,235,840 B
    unsigned short* AOb = (unsigned short*)(ws + 11100160);         // 2,621,440 B
    unsigned short* Wb  = (unsigned short*)(ws + 13721600);         //   655,360 B
    int*       maskflag = (int*)           (ws + 14376960);

    detect_mask_kernel<<<1, 64, 0, stream>>>((const unsigned*)mask, maskflag);
    pack_mask_kernel<<<dim3(20, NKT_PAD), 256, 0, stream>>>(mask, maskflag, pmT);
    wb16_kernel<<<dim3(64, 5), 256, 0, stream>>>(w_in, wq, wk, wv, w_out, Wb);
    embed_qkv_kernel<<<dim3(NKT, 3), 256, 0, stream>>>(
        x, ctx, row_embed, col_embed, Wb, b_in, bq, bk, bv, Qb, Kb, Vt);
    attn_mfma_kernel<<<dim3(NKT * 8), 512, 0, stream>>>(Qb, Kb, Vt, pmT, AOb);
    proj_out_kernel<<<dim3(NKT, 8), 64, 0, stream>>>(AOb, Wb + 4 * 65536, b_out, out);
}